// Round 1
// baseline (624.985 us; speedup 1.0000x reference)
//
#include <hip/hip_runtime.h>

#define BB 8
#define NN 8192
#define SS 2048
#define DD1 64
#define DD2 128
#define CIN 192
#define CH1 256
#define CH2 128
#define RTOT (BB*NN)   // 65536

// ---------- generic batched 2D transpose: in [b][rows][cols] -> out [b][cols][rows] ----------
__global__ void transpose_k(const float* __restrict__ in, float* __restrict__ out,
                            int rows, int cols) {
  __shared__ float tile[32][33];
  int b = blockIdx.z;
  const float* src = in + (size_t)b * rows * cols;
  float* dst = out + (size_t)b * rows * cols;
  int c0 = blockIdx.x * 32, r0 = blockIdx.y * 32;
  for (int i = threadIdx.y; i < 32; i += 8)
    tile[i][threadIdx.x] = src[(size_t)(r0 + i) * cols + (c0 + threadIdx.x)];
  __syncthreads();
  for (int i = threadIdx.y; i < 32; i += 8)
    dst[(size_t)(c0 + i) * rows + (r0 + threadIdx.x)] = tile[threadIdx.x][i];
}

// ---------- 3-NN in fp64 (ranking must match numpy reference) ----------
__global__ __launch_bounds__(128) void knn3(const float* __restrict__ xyz1,
                                            const float* __restrict__ xyz2,
                                            int* __restrict__ idx3,
                                            float* __restrict__ w3) {
  __shared__ float sx[SS], sy[SS], sz[SS];
  int r = blockIdx.x * 128 + threadIdx.x;
  int b = r >> 13;           // N = 8192
  int n = r & (NN - 1);
  const float* x2 = xyz2 + (size_t)b * 3 * SS;
  for (int i = threadIdx.x; i < SS; i += 128) {
    sx[i] = x2[i];
    sy[i] = x2[SS + i];
    sz[i] = x2[2 * SS + i];
  }
  __syncthreads();
  const float* x1 = xyz1 + (size_t)b * 3 * NN;
  double px = (double)x1[n];
  double py = (double)x1[NN + n];
  double pz = (double)x1[2 * NN + n];
  double d0 = 1e300, d1 = 1e300, d2 = 1e300;
  int i0 = 0, i1 = 0, i2 = 0;
#pragma unroll 4
  for (int s = 0; s < SS; ++s) {
    double dx = (double)sx[s] - px;
    double dy = (double)sy[s] - py;
    double dz = (double)sz[s] - pz;
    double d = dx * dx + dy * dy + dz * dz;
    if (d < d2) {
      if (d < d1) {
        d2 = d1; i2 = i1;
        if (d < d0) { d1 = d0; i1 = i0; d0 = d; i0 = s; }
        else        { d1 = d;  i1 = s; }
      } else { d2 = d; i2 = s; }
    }
  }
  double r0 = 1.0 / (d0 + 1e-8), r1 = 1.0 / (d1 + 1e-8), r2 = 1.0 / (d2 + 1e-8);
  double sw = r0 + r1 + r2;
  idx3[r * 3 + 0] = i0; idx3[r * 3 + 1] = i1; idx3[r * 3 + 2] = i2;
  w3[r * 3 + 0] = (float)(r0 / sw);
  w3[r * 3 + 1] = (float)(r1 / sw);
  w3[r * 3 + 2] = (float)(r2 / sw);
}

// ---------- build H0 [R x 192] = concat(p1t[r, 0:64], interp[r, 0:128]) ----------
__global__ void gather_h0(const float* __restrict__ p1t, const float* __restrict__ p2t,
                          const int* __restrict__ idx3, const float* __restrict__ w3,
                          float* __restrict__ H0) {
  int r = blockIdx.x * blockDim.y + threadIdx.y;
  int c = threadIdx.x;   // 0..191
  int b = r >> 13;
  if (c < DD1) {
    H0[(size_t)r * CIN + c] = p1t[(size_t)r * DD1 + c];
  } else {
    int cc = c - DD1;
    int i0 = idx3[r * 3], i1 = idx3[r * 3 + 1], i2 = idx3[r * 3 + 2];
    float w0 = w3[r * 3], w1 = w3[r * 3 + 1], w2 = w3[r * 3 + 2];
    const float* base = p2t + (size_t)b * SS * DD2;
    float v = w0 * base[(size_t)i0 * DD2 + cc]
            + w1 * base[(size_t)i1 * DD2 + cc]
            + w2 * base[(size_t)i2 * DD2 + cc];
    H0[(size_t)r * CIN + c] = v;
  }
}

// ---------- fp32 tiled GEMM: C[M x Nc] = op(A)[M x K] @ Bw[K x Nc] + bias ----------
// BNFUSE=1: A element -> relu(a0[k]*A + c0[k])  (layer-0 BN+ReLU fused into layer-1 input)
template <int BNFUSE>
__global__ __launch_bounds__(256) void gemm_tile(const float* __restrict__ A,
                                                 const float* __restrict__ Bw,
                                                 const float* __restrict__ bias,
                                                 const float* __restrict__ a0,
                                                 const float* __restrict__ c0,
                                                 float* __restrict__ C,
                                                 int M, int Nc, int K) {
  __shared__ float As[16][65];
  __shared__ float Bs[16][64];
  int tid = threadIdx.x;
  int bm = blockIdx.y * 64, bn = blockIdx.x * 64;
  int tx = tid & 15, ty = tid >> 4;
  float acc[4][4] = {};
  for (int k0 = 0; k0 < K; k0 += 16) {
#pragma unroll
    for (int i = 0; i < 4; ++i) {
      int l = tid + i * 256;
      int m = l >> 4, k = l & 15;
      float v = A[(size_t)(bm + m) * K + k0 + k];
      if (BNFUSE) v = fmaxf(fmaf(v, a0[k0 + k], c0[k0 + k]), 0.f);
      As[k][m] = v;
    }
#pragma unroll
    for (int i = 0; i < 4; ++i) {
      int l = tid + i * 256;
      int n = l & 63, k = l >> 6;
      Bs[k][n] = Bw[(size_t)(k0 + k) * Nc + bn + n];
    }
    __syncthreads();
#pragma unroll
    for (int kk = 0; kk < 16; ++kk) {
      float av[4], bv[4];
#pragma unroll
      for (int i = 0; i < 4; ++i) av[i] = As[kk][ty * 4 + i];
#pragma unroll
      for (int j = 0; j < 4; ++j) bv[j] = Bs[kk][tx * 4 + j];
#pragma unroll
      for (int i = 0; i < 4; ++i)
#pragma unroll
        for (int j = 0; j < 4; ++j) acc[i][j] += av[i] * bv[j];
    }
    __syncthreads();
  }
#pragma unroll
  for (int i = 0; i < 4; ++i) {
    int m = bm + ty * 4 + i;
#pragma unroll
    for (int j = 0; j < 4; ++j) {
      int n = bn + tx * 4 + j;
      C[(size_t)m * Nc + n] = acc[i][j] + bias[n];
    }
  }
}

// ---------- per-channel sum / sumsq over rows (thread = channel, coalesced) ----------
__global__ void colstats(const float* __restrict__ Z, int Rr, int C,
                         float* __restrict__ sum, float* __restrict__ sumsq) {
  int c = threadIdx.x;
  int rows = Rr / gridDim.x;
  int r0 = blockIdx.x * rows;
  float s = 0.f, q = 0.f;
  for (int r = r0; r < r0 + rows; ++r) {
    float v = Z[(size_t)r * C + c];
    s += v; q += v * v;
  }
  atomicAdd(&sum[c], s);
  atomicAdd(&sumsq[c], q);
}

__global__ void finalize_bn(const float* __restrict__ sum, const float* __restrict__ sumsq,
                            const float* __restrict__ scale, const float* __restrict__ bias,
                            float* __restrict__ a, float* __restrict__ c,
                            int C, float invR) {
  int j = threadIdx.x;
  if (j >= C) return;
  float mu = sum[j] * invR;
  float var = sumsq[j] * invR - mu * mu;
  float aa = scale[j] * (1.0f / sqrtf(var + 1e-5f));
  a[j] = aa;
  c[j] = bias[j] - mu * aa;
}

// ---------- BN+ReLU + transpose to [B, 128, N] ----------
__global__ void out_bn_transpose(const float* __restrict__ Z1,
                                 const float* __restrict__ a, const float* __restrict__ c,
                                 float* __restrict__ out) {
  __shared__ float tile[32][33];
  int b = blockIdx.z;
  const float* src = Z1 + (size_t)b * NN * CH2;
  float* dst = out + (size_t)b * CH2 * NN;
  int c0 = blockIdx.x * 32, n0 = blockIdx.y * 32;
  for (int i = threadIdx.y; i < 32; i += 8) {
    int n = n0 + i, ch = c0 + threadIdx.x;
    float v = src[(size_t)n * CH2 + ch];
    v = fmaxf(fmaf(v, a[ch], c[ch]), 0.f);
    tile[i][threadIdx.x] = v;
  }
  __syncthreads();
  for (int i = threadIdx.y; i < 32; i += 8) {
    int ch = c0 + i, n = n0 + threadIdx.x;
    dst[(size_t)ch * NN + n] = tile[threadIdx.x][i];
  }
}

extern "C" void kernel_launch(void* const* d_in, const int* in_sizes, int n_in,
                              void* d_out, int out_size, void* d_ws, size_t ws_size,
                              hipStream_t stream) {
  const float* xyz1    = (const float*)d_in[0];
  const float* xyz2    = (const float*)d_in[1];
  const float* points1 = (const float*)d_in[2];
  const float* points2 = (const float*)d_in[3];
  const float* w0  = (const float*)d_in[4];
  const float* cb0 = (const float*)d_in[5];
  const float* s0  = (const float*)d_in[6];
  const float* bb0 = (const float*)d_in[7];
  const float* w1  = (const float*)d_in[8];
  const float* cb1 = (const float*)d_in[9];
  const float* s1  = (const float*)d_in[10];
  const float* bb1 = (const float*)d_in[11];

  float* ws = (float*)d_ws;
  // layout (floats)
  float* p2t   = ws;                        // 2,097,152
  int*   idx3  = (int*)(ws + 2097152);      //   196,608
  float* w3    = ws + 2293760;              //   196,608
  float* p1t   = ws + 2490368;              // 4,194,304
  float* H0    = ws + 6684672;              // 12,582,912
  float* Z0    = ws + 19267584;             // 16,777,216
  float* stats = ws + 36044800;             //     1,536
  float* Z1    = ws + 2490368;              // aliases p1t/H0 prefix (dead after GEMM1)

  float* sum0 = stats;        float* sq0 = stats + 256;
  float* a0c  = stats + 512;  float* c0c = stats + 768;
  float* sum1 = stats + 1024; float* sq1 = stats + 1152;
  float* a1c  = stats + 1280; float* c1c = stats + 1408;

  hipMemsetAsync(stats, 0, 1536 * sizeof(float), stream);

  // points2 [B,128,S] -> p2t [B,S,128];  points1 [B,64,N] -> p1t [B,N,64]
  transpose_k<<<dim3(SS / 32, DD2 / 32, BB), dim3(32, 8), 0, stream>>>(points2, p2t, DD2, SS);
  transpose_k<<<dim3(NN / 32, DD1 / 32, BB), dim3(32, 8), 0, stream>>>(points1, p1t, DD1, NN);

  knn3<<<RTOT / 128, 128, 0, stream>>>(xyz1, xyz2, idx3, w3);

  gather_h0<<<RTOT / 2, dim3(192, 2), 0, stream>>>(p1t, p2t, idx3, w3, H0);

  // layer 0: Z0 = H0 @ W0 + b0
  gemm_tile<0><<<dim3(CH1 / 64, RTOT / 64), 256, 0, stream>>>(H0, w0, cb0, nullptr, nullptr,
                                                              Z0, RTOT, CH1, CIN);
  colstats<<<512, CH1, 0, stream>>>(Z0, RTOT, CH1, sum0, sq0);
  finalize_bn<<<1, CH1, 0, stream>>>(sum0, sq0, s0, bb0, a0c, c0c, CH1, 1.0f / RTOT);

  // layer 1: Z1 = relu(BN(Z0)) @ W1 + b1   (BN+ReLU fused into A load)
  gemm_tile<1><<<dim3(CH2 / 64, RTOT / 64), 256, 0, stream>>>(Z0, w1, cb1, a0c, c0c,
                                                              Z1, RTOT, CH2, CH1);
  colstats<<<512, CH2, 0, stream>>>(Z1, RTOT, CH2, sum1, sq1);
  finalize_bn<<<1, CH2, 0, stream>>>(sum1, sq1, s1, bb1, a1c, c1c, CH2, 1.0f / RTOT);

  out_bn_transpose<<<dim3(CH2 / 32, NN / 32, BB), dim3(32, 8), 0, stream>>>(Z1, a1c, c1c,
                                                                            (float*)d_out);
}

// Round 2
// 491.733 us; speedup vs baseline: 1.2710x; 1.2710x over previous
//
#include <hip/hip_runtime.h>

#define BB 8
#define NN 8192
#define SS 2048
#define DD1 64
#define DD2 128
#define CIN 192
#define CH1 256
#define CH2 128
#define RTOT (BB*NN)   // 65536
#define KCHUNK 512
#define NCHK 4

// ---------- generic batched 2D transpose: in [b][rows][cols] -> out [b][cols][rows] ----------
__global__ void transpose_k(const float* __restrict__ in, float* __restrict__ out,
                            int rows, int cols) {
  __shared__ float tile[32][33];
  int b = blockIdx.z;
  const float* src = in + (size_t)b * rows * cols;
  float* dst = out + (size_t)b * rows * cols;
  int c0 = blockIdx.x * 32, r0 = blockIdx.y * 32;
  for (int i = threadIdx.y; i < 32; i += 8)
    tile[i][threadIdx.x] = src[(size_t)(r0 + i) * cols + (c0 + threadIdx.x)];
  __syncthreads();
  for (int i = threadIdx.y; i < 32; i += 8)
    dst[(size_t)(c0 + i) * rows + (r0 + threadIdx.x)] = tile[threadIdx.x][i];
}

// ---------- 3-NN in fp64, split-S for occupancy ----------
// block = 256 threads = 64 rows x 4 chunks of 512 source points.
// Per-thread top-3 over its chunk, then LDS merge in chunk order (strict <
// insertion reproduces top_k's lowest-index tie-break).
__global__ __launch_bounds__(256) void knn3(const float* __restrict__ xyz1,
                                            const float* __restrict__ xyz2,
                                            int* __restrict__ idx3,
                                            float* __restrict__ w3) {
  __shared__ float sx[SS], sy[SS], sz[SS];
  __shared__ double cd[NCHK][64][3];
  __shared__ int    ci[NCHK][64][3];
  int tid = threadIdx.x;
  int r0 = blockIdx.x * 64;          // 64 rows per block, same batch (8192 % 64 == 0)
  int b = r0 >> 13;                  // N = 8192
  const float* x2 = xyz2 + (size_t)b * 3 * SS;
  for (int i = tid; i < SS; i += 256) {
    sx[i] = x2[i];
    sy[i] = x2[SS + i];
    sz[i] = x2[2 * SS + i];
  }
  __syncthreads();
  int row = tid & 63, chk = tid >> 6;   // wave-uniform chunk -> LDS broadcast reads
  int n = (r0 & (NN - 1)) + row;
  const float* x1 = xyz1 + (size_t)b * 3 * NN;
  double px = (double)x1[n];
  double py = (double)x1[NN + n];
  double pz = (double)x1[2 * NN + n];
  double d0 = 1e300, d1 = 1e300, d2 = 1e300;
  int i0 = 0, i1 = 0, i2 = 0;
  int sbeg = chk * KCHUNK;
#pragma unroll 4
  for (int s = sbeg; s < sbeg + KCHUNK; ++s) {
    double dx = (double)sx[s] - px;
    double dy = (double)sy[s] - py;
    double dz = (double)sz[s] - pz;
    double d = dx * dx + dy * dy + dz * dz;
    if (d < d2) {
      if (d < d1) {
        d2 = d1; i2 = i1;
        if (d < d0) { d1 = d0; i1 = i0; d0 = d; i0 = s; }
        else        { d1 = d;  i1 = s; }
      } else { d2 = d; i2 = s; }
    }
  }
  cd[chk][row][0] = d0; cd[chk][row][1] = d1; cd[chk][row][2] = d2;
  ci[chk][row][0] = i0; ci[chk][row][1] = i1; ci[chk][row][2] = i2;
  __syncthreads();
  if (tid < 64) {
    double e0 = 1e300, e1 = 1e300, e2 = 1e300;
    int j0 = 0, j1 = 0, j2 = 0;
#pragma unroll
    for (int c = 0; c < NCHK; ++c)
#pragma unroll
      for (int t = 0; t < 3; ++t) {
        double d = cd[c][tid][t];
        int si = ci[c][tid][t];
        if (d < e2) {
          if (d < e1) {
            e2 = e1; j2 = j1;
            if (d < e0) { e1 = e0; j1 = j0; e0 = d; j0 = si; }
            else        { e1 = d;  j1 = si; }
          } else { e2 = d; j2 = si; }
        }
      }
    double rr0 = 1.0 / (e0 + 1e-8), rr1 = 1.0 / (e1 + 1e-8), rr2 = 1.0 / (e2 + 1e-8);
    double sw = rr0 + rr1 + rr2;
    int r = r0 + tid;
    idx3[r * 3 + 0] = j0; idx3[r * 3 + 1] = j1; idx3[r * 3 + 2] = j2;
    w3[r * 3 + 0] = (float)(rr0 / sw);
    w3[r * 3 + 1] = (float)(rr1 / sw);
    w3[r * 3 + 2] = (float)(rr2 / sw);
  }
}

// ---------- build H0 [R x 192] = concat(p1t[r, 0:64], interp[r, 0:128]) ----------
__global__ void gather_h0(const float* __restrict__ p1t, const float* __restrict__ p2t,
                          const int* __restrict__ idx3, const float* __restrict__ w3,
                          float* __restrict__ H0) {
  int r = blockIdx.x * blockDim.y + threadIdx.y;
  int c = threadIdx.x;   // 0..191
  int b = r >> 13;
  if (c < DD1) {
    H0[(size_t)r * CIN + c] = p1t[(size_t)r * DD1 + c];
  } else {
    int cc = c - DD1;
    int i0 = idx3[r * 3], i1 = idx3[r * 3 + 1], i2 = idx3[r * 3 + 2];
    float w0 = w3[r * 3], w1 = w3[r * 3 + 1], w2 = w3[r * 3 + 2];
    const float* base = p2t + (size_t)b * SS * DD2;
    float v = w0 * base[(size_t)i0 * DD2 + cc]
            + w1 * base[(size_t)i1 * DD2 + cc]
            + w2 * base[(size_t)i2 * DD2 + cc];
    H0[(size_t)r * CIN + c] = v;
  }
}

// ---------- fp32 tiled GEMM: C[M x Nc] = op(A)[M x K] @ Bw[K x Nc] + bias ----------
// BNFUSE=1: A element -> relu(a0[k]*A + c0[k])  (layer-0 BN+ReLU fused into layer-1 input)
template <int BNFUSE>
__global__ __launch_bounds__(256) void gemm_tile(const float* __restrict__ A,
                                                 const float* __restrict__ Bw,
                                                 const float* __restrict__ bias,
                                                 const float* __restrict__ a0,
                                                 const float* __restrict__ c0,
                                                 float* __restrict__ C,
                                                 int M, int Nc, int K) {
  __shared__ float As[16][65];
  __shared__ float Bs[16][64];
  int tid = threadIdx.x;
  int bm = blockIdx.y * 64, bn = blockIdx.x * 64;
  int tx = tid & 15, ty = tid >> 4;
  float acc[4][4] = {};
  for (int k0 = 0; k0 < K; k0 += 16) {
#pragma unroll
    for (int i = 0; i < 4; ++i) {
      int l = tid + i * 256;
      int m = l >> 4, k = l & 15;
      float v = A[(size_t)(bm + m) * K + k0 + k];
      if (BNFUSE) v = fmaxf(fmaf(v, a0[k0 + k], c0[k0 + k]), 0.f);
      As[k][m] = v;
    }
#pragma unroll
    for (int i = 0; i < 4; ++i) {
      int l = tid + i * 256;
      int n = l & 63, k = l >> 6;
      Bs[k][n] = Bw[(size_t)(k0 + k) * Nc + bn + n];
    }
    __syncthreads();
#pragma unroll
    for (int kk = 0; kk < 16; ++kk) {
      float av[4], bv[4];
#pragma unroll
      for (int i = 0; i < 4; ++i) av[i] = As[kk][ty * 4 + i];
#pragma unroll
      for (int j = 0; j < 4; ++j) bv[j] = Bs[kk][tx * 4 + j];
#pragma unroll
      for (int i = 0; i < 4; ++i)
#pragma unroll
        for (int j = 0; j < 4; ++j) acc[i][j] += av[i] * bv[j];
    }
    __syncthreads();
  }
#pragma unroll
  for (int i = 0; i < 4; ++i) {
    int m = bm + ty * 4 + i;
#pragma unroll
    for (int j = 0; j < 4; ++j) {
      int n = bn + tx * 4 + j;
      C[(size_t)m * Nc + n] = acc[i][j] + bias[n];
    }
  }
}

// ---------- per-channel sum / sumsq over rows (thread = channel, coalesced) ----------
__global__ void colstats(const float* __restrict__ Z, int Rr, int C,
                         float* __restrict__ sum, float* __restrict__ sumsq) {
  int c = threadIdx.x;
  int rows = Rr / gridDim.x;
  int r0 = blockIdx.x * rows;
  float s = 0.f, q = 0.f;
  for (int r = r0; r < r0 + rows; ++r) {
    float v = Z[(size_t)r * C + c];
    s += v; q += v * v;
  }
  atomicAdd(&sum[c], s);
  atomicAdd(&sumsq[c], q);
}

__global__ void finalize_bn(const float* __restrict__ sum, const float* __restrict__ sumsq,
                            const float* __restrict__ scale, const float* __restrict__ bias,
                            float* __restrict__ a, float* __restrict__ c,
                            int C, float invR) {
  int j = threadIdx.x;
  if (j >= C) return;
  float mu = sum[j] * invR;
  float var = sumsq[j] * invR - mu * mu;
  float aa = scale[j] * (1.0f / sqrtf(var + 1e-5f));
  a[j] = aa;
  c[j] = bias[j] - mu * aa;
}

// ---------- BN+ReLU + transpose to [B, 128, N] ----------
__global__ void out_bn_transpose(const float* __restrict__ Z1,
                                 const float* __restrict__ a, const float* __restrict__ c,
                                 float* __restrict__ out) {
  __shared__ float tile[32][33];
  int b = blockIdx.z;
  const float* src = Z1 + (size_t)b * NN * CH2;
  float* dst = out + (size_t)b * CH2 * NN;
  int c0 = blockIdx.x * 32, n0 = blockIdx.y * 32;
  for (int i = threadIdx.y; i < 8 * 4; i += 8) {
    int n = n0 + i, ch = c0 + threadIdx.x;
    float v = src[(size_t)n * CH2 + ch];
    v = fmaxf(fmaf(v, a[ch], c[ch]), 0.f);
    tile[i][threadIdx.x] = v;
  }
  __syncthreads();
  for (int i = threadIdx.y; i < 32; i += 8) {
    int ch = c0 + i, n = n0 + threadIdx.x;
    dst[(size_t)ch * NN + n] = tile[threadIdx.x][i];
  }
}

extern "C" void kernel_launch(void* const* d_in, const int* in_sizes, int n_in,
                              void* d_out, int out_size, void* d_ws, size_t ws_size,
                              hipStream_t stream) {
  const float* xyz1    = (const float*)d_in[0];
  const float* xyz2    = (const float*)d_in[1];
  const float* points1 = (const float*)d_in[2];
  const float* points2 = (const float*)d_in[3];
  const float* w0  = (const float*)d_in[4];
  const float* cb0 = (const float*)d_in[5];
  const float* s0  = (const float*)d_in[6];
  const float* bb0 = (const float*)d_in[7];
  const float* w1  = (const float*)d_in[8];
  const float* cb1 = (const float*)d_in[9];
  const float* s1  = (const float*)d_in[10];
  const float* bb1 = (const float*)d_in[11];

  float* ws = (float*)d_ws;
  // layout (floats)
  float* p2t   = ws;                        // 2,097,152
  int*   idx3  = (int*)(ws + 2097152);      //   196,608
  float* w3    = ws + 2293760;              //   196,608
  float* p1t   = ws + 2490368;              // 4,194,304
  float* H0    = ws + 6684672;              // 12,582,912
  float* Z0    = ws + 19267584;             // 16,777,216
  float* stats = ws + 36044800;             //     1,536
  float* Z1    = ws + 2490368;              // aliases p1t/H0 prefix (dead after GEMM1)

  float* sum0 = stats;        float* sq0 = stats + 256;
  float* a0c  = stats + 512;  float* c0c = stats + 768;
  float* sum1 = stats + 1024; float* sq1 = stats + 1152;
  float* a1c  = stats + 1280; float* c1c = stats + 1408;

  hipMemsetAsync(stats, 0, 1536 * sizeof(float), stream);

  // points2 [B,128,S] -> p2t [B,S,128];  points1 [B,64,N] -> p1t [B,N,64]
  transpose_k<<<dim3(SS / 32, DD2 / 32, BB), dim3(32, 8), 0, stream>>>(points2, p2t, DD2, SS);
  transpose_k<<<dim3(NN / 32, DD1 / 32, BB), dim3(32, 8), 0, stream>>>(points1, p1t, DD1, NN);

  knn3<<<RTOT / 64, 256, 0, stream>>>(xyz1, xyz2, idx3, w3);

  gather_h0<<<RTOT / 2, dim3(192, 2), 0, stream>>>(p1t, p2t, idx3, w3, H0);

  // layer 0: Z0 = H0 @ W0 + b0
  gemm_tile<0><<<dim3(CH1 / 64, RTOT / 64), 256, 0, stream>>>(H0, w0, cb0, nullptr, nullptr,
                                                              Z0, RTOT, CH1, CIN);
  colstats<<<512, CH1, 0, stream>>>(Z0, RTOT, CH1, sum0, sq0);
  finalize_bn<<<1, CH1, 0, stream>>>(sum0, sq0, s0, bb0, a0c, c0c, CH1, 1.0f / RTOT);

  // layer 1: Z1 = relu(BN(Z0)) @ W1 + b1   (BN+ReLU fused into A load)
  gemm_tile<1><<<dim3(CH2 / 64, RTOT / 64), 256, 0, stream>>>(Z0, w1, cb1, a0c, c0c,
                                                              Z1, RTOT, CH2, CH1);
  colstats<<<512, CH2, 0, stream>>>(Z1, RTOT, CH2, sum1, sq1);
  finalize_bn<<<1, CH2, 0, stream>>>(sum1, sq1, s1, bb1, a1c, c1c, CH2, 1.0f / RTOT);

  out_bn_transpose<<<dim3(CH2 / 32, NN / 32, BB), dim3(32, 8), 0, stream>>>(Z1, a1c, c1c,
                                                                            (float*)d_out);
}

// Round 3
// 362.917 us; speedup vs baseline: 1.7221x; 1.3549x over previous
//
#include <hip/hip_runtime.h>

#define BB 8
#define NN 8192
#define SS 2048
#define DD1 64
#define DD2 128
#define CIN 192
#define CH1 256
#define CH2 128
#define RTOT (BB*NN)   // 65536
#define KCHUNK 512
#define NCHK 4

typedef __attribute__((ext_vector_type(8))) short short8;
typedef __attribute__((ext_vector_type(4))) float floatx4;

__device__ __forceinline__ unsigned short f2bf(float f) {
  unsigned u = __float_as_uint(f);
  u += 0x7fff + ((u >> 16) & 1);   // round-to-nearest-even
  return (unsigned short)(u >> 16);
}
__device__ __forceinline__ float bf2f(unsigned short h) {
  return __uint_as_float(((unsigned)h) << 16);
}

// ---------- batched 2D transpose fp32: in [b][rows][cols] -> out [b][cols][rows] ----------
__global__ void transpose_k(const float* __restrict__ in, float* __restrict__ out,
                            int rows, int cols) {
  __shared__ float tile[32][33];
  int b = blockIdx.z;
  const float* src = in + (size_t)b * rows * cols;
  float* dst = out + (size_t)b * rows * cols;
  int c0 = blockIdx.x * 32, r0 = blockIdx.y * 32;
  for (int i = threadIdx.y; i < 32; i += 8)
    tile[i][threadIdx.x] = src[(size_t)(r0 + i) * cols + (c0 + threadIdx.x)];
  __syncthreads();
  for (int i = threadIdx.y; i < 32; i += 8)
    dst[(size_t)(c0 + i) * rows + (r0 + threadIdx.x)] = tile[threadIdx.x][i];
}

// ---------- transpose + fp32->bf16 (for weights; out is [cols][rows] bf16) ----------
__global__ void transpose_cvt(const float* __restrict__ in, unsigned short* __restrict__ out,
                              int rows, int cols) {
  __shared__ float tile[32][33];
  int c0 = blockIdx.x * 32, r0 = blockIdx.y * 32;
  for (int i = threadIdx.y; i < 32; i += 8)
    tile[i][threadIdx.x] = in[(size_t)(r0 + i) * cols + (c0 + threadIdx.x)];
  __syncthreads();
  for (int i = threadIdx.y; i < 32; i += 8)
    out[(size_t)(c0 + i) * rows + (r0 + threadIdx.x)] = f2bf(tile[threadIdx.x][i]);
}

// ---------- 3-NN in fp64, split-S for occupancy ----------
__global__ __launch_bounds__(256) void knn3(const float* __restrict__ xyz1,
                                            const float* __restrict__ xyz2,
                                            int* __restrict__ idx3,
                                            float* __restrict__ w3) {
  __shared__ float sx[SS], sy[SS], sz[SS];
  __shared__ double cd[NCHK][64][3];
  __shared__ int    ci[NCHK][64][3];
  int tid = threadIdx.x;
  int r0 = blockIdx.x * 64;
  int b = r0 >> 13;
  const float* x2 = xyz2 + (size_t)b * 3 * SS;
  for (int i = tid; i < SS; i += 256) {
    sx[i] = x2[i];
    sy[i] = x2[SS + i];
    sz[i] = x2[2 * SS + i];
  }
  __syncthreads();
  int row = tid & 63, chk = tid >> 6;
  int n = (r0 & (NN - 1)) + row;
  const float* x1 = xyz1 + (size_t)b * 3 * NN;
  double px = (double)x1[n];
  double py = (double)x1[NN + n];
  double pz = (double)x1[2 * NN + n];
  double d0 = 1e300, d1 = 1e300, d2 = 1e300;
  int i0 = 0, i1 = 0, i2 = 0;
  int sbeg = chk * KCHUNK;
#pragma unroll 4
  for (int s = sbeg; s < sbeg + KCHUNK; ++s) {
    double dx = (double)sx[s] - px;
    double dy = (double)sy[s] - py;
    double dz = (double)sz[s] - pz;
    double d = dx * dx + dy * dy + dz * dz;
    if (d < d2) {
      if (d < d1) {
        d2 = d1; i2 = i1;
        if (d < d0) { d1 = d0; i1 = i0; d0 = d; i0 = s; }
        else        { d1 = d;  i1 = s; }
      } else { d2 = d; i2 = s; }
    }
  }
  cd[chk][row][0] = d0; cd[chk][row][1] = d1; cd[chk][row][2] = d2;
  ci[chk][row][0] = i0; ci[chk][row][1] = i1; ci[chk][row][2] = i2;
  __syncthreads();
  if (tid < 64) {
    double e0 = 1e300, e1 = 1e300, e2 = 1e300;
    int j0 = 0, j1 = 0, j2 = 0;
#pragma unroll
    for (int c = 0; c < NCHK; ++c)
#pragma unroll
      for (int t = 0; t < 3; ++t) {
        double d = cd[c][tid][t];
        int si = ci[c][tid][t];
        if (d < e2) {
          if (d < e1) {
            e2 = e1; j2 = j1;
            if (d < e0) { e1 = e0; j1 = j0; e0 = d; j0 = si; }
            else        { e1 = d;  j1 = si; }
          } else { e2 = d; j2 = si; }
        }
      }
    double rr0 = 1.0 / (e0 + 1e-8), rr1 = 1.0 / (e1 + 1e-8), rr2 = 1.0 / (e2 + 1e-8);
    double sw = rr0 + rr1 + rr2;
    int r = r0 + tid;
    idx3[r * 3 + 0] = j0; idx3[r * 3 + 1] = j1; idx3[r * 3 + 2] = j2;
    w3[r * 3 + 0] = (float)(rr0 / sw);
    w3[r * 3 + 1] = (float)(rr1 / sw);
    w3[r * 3 + 2] = (float)(rr2 / sw);
  }
}

// ---------- build H0 bf16 [R x 192] = concat(p1t, interp) ----------
__global__ void gather_h0(const float* __restrict__ p1t, const float* __restrict__ p2t,
                          const int* __restrict__ idx3, const float* __restrict__ w3,
                          unsigned short* __restrict__ H0) {
  int r = blockIdx.x * blockDim.y + threadIdx.y;
  int c = threadIdx.x;   // 0..191
  int b = r >> 13;
  float v;
  if (c < DD1) {
    v = p1t[(size_t)r * DD1 + c];
  } else {
    int cc = c - DD1;
    int i0 = idx3[r * 3], i1 = idx3[r * 3 + 1], i2 = idx3[r * 3 + 2];
    float w0 = w3[r * 3], w1 = w3[r * 3 + 1], w2 = w3[r * 3 + 2];
    const float* base = p2t + (size_t)b * SS * DD2;
    v = w0 * base[(size_t)i0 * DD2 + cc]
      + w1 * base[(size_t)i1 * DD2 + cc]
      + w2 * base[(size_t)i2 * DD2 + cc];
  }
  H0[(size_t)r * CIN + c] = f2bf(v);
}

// ---------- bf16 MFMA GEMM: C[M x Nc] = op(A) @ BT^T + bias, all bf16 in, bf16 out ----------
// A [M x K] bf16 row-major; BT [Nc x K] bf16 (weights pre-transposed).
// BNFUSE=1: A element -> bf16(relu(a0[k]*A + c0[k])), staged via VGPRs.
// Tile 128x128, 4 waves, each wave 4x4 of 16x16x32 MFMA. BK=32.
// LDS tiles [128][32] bf16, chunk-swizzled: kc_phys = kc ^ ((row>>2)&3)
// so global_load_lds (no padding allowed) still gives 2-way-max ds_read_b128.
template<int BNFUSE, int K>
__global__ __launch_bounds__(256) void gemm_mfma(
    const unsigned short* __restrict__ A,
    const unsigned short* __restrict__ BT,
    const float* __restrict__ bias,
    const float* __restrict__ a0, const float* __restrict__ c0,
    unsigned short* __restrict__ C, int Nc)
{
  __shared__ __align__(16) unsigned short As[128 * 32];
  __shared__ __align__(16) unsigned short Bs[128 * 32];
  __shared__ float sa[BNFUSE ? 256 : 1];
  __shared__ float sc[BNFUSE ? 256 : 1];
  int tid = threadIdx.x;
  int lane = tid & 63, w = tid >> 6;
  int bn = blockIdx.x << 7, bm = blockIdx.y << 7;
  int wm = (w & 1) << 6, wn = (w >> 1) << 6;
  if (BNFUSE) {
    for (int i = tid; i < K; i += 256) { sa[i] = a0[i]; sc[i] = c0[i]; }
    __syncthreads();
  }
  floatx4 acc[4][4] = {};   // [mt][nt]
  for (int k0 = 0; k0 < K; k0 += 32) {
    if (!BNFUSE) {
#pragma unroll
      for (int t = 0; t < 2; ++t) {
        int s = (w * 2 + t) * 64 + lane;
        int r = s >> 2;
        int kc = (s & 3) ^ ((r >> 2) & 3);
        const unsigned short* gp = A + (size_t)(bm + r) * K + (k0 + kc * 8);
        __builtin_amdgcn_global_load_lds(
            (const __attribute__((address_space(1))) void*)gp,
            (__attribute__((address_space(3))) void*)(As + (w * 2 + t) * 512),
            16, 0, 0);
      }
    } else {
#pragma unroll
      for (int t = 0; t < 2; ++t) {
        int s = t * 256 + tid;
        int r = s >> 2;
        int kc = (s & 3) ^ ((r >> 2) & 3);
        int kg = k0 + kc * 8;
        short8 raw = *(const short8*)(A + (size_t)(bm + r) * K + kg);
        short8 ov;
#pragma unroll
        for (int j = 0; j < 8; ++j) {
          float v = bf2f((unsigned short)raw[j]);
          v = fmaxf(fmaf(v, sa[kg + j], sc[kg + j]), 0.f);
          ov[j] = (short)f2bf(v);
        }
        *(short8*)(As + s * 8) = ov;
      }
    }
#pragma unroll
    for (int t = 0; t < 2; ++t) {
      int s = (w * 2 + t) * 64 + lane;
      int r = s >> 2;
      int kc = (s & 3) ^ ((r >> 2) & 3);
      const unsigned short* gp = BT + (size_t)(bn + r) * K + (k0 + kc * 8);
      __builtin_amdgcn_global_load_lds(
          (const __attribute__((address_space(1))) void*)gp,
          (__attribute__((address_space(3))) void*)(Bs + (w * 2 + t) * 512),
          16, 0, 0);
    }
    __syncthreads();
    {
      short8 af[4], bfr[4];
      int kcl = lane >> 4;
      int lm = lane & 15;
#pragma unroll
      for (int mt = 0; mt < 4; ++mt) {
        int r = wm + mt * 16 + lm;
        int kp = kcl ^ ((r >> 2) & 3);
        af[mt] = *(const short8*)(As + r * 32 + kp * 8);
      }
#pragma unroll
      for (int nt = 0; nt < 4; ++nt) {
        int r = wn + nt * 16 + lm;
        int kp = kcl ^ ((r >> 2) & 3);
        bfr[nt] = *(const short8*)(Bs + r * 32 + kp * 8);
      }
#pragma unroll
      for (int mt = 0; mt < 4; ++mt)
#pragma unroll
        for (int nt = 0; nt < 4; ++nt)
          acc[mt][nt] = __builtin_amdgcn_mfma_f32_16x16x32_bf16(af[mt], bfr[nt], acc[mt][nt], 0, 0, 0);
    }
    __syncthreads();
  }
  // epilogue: C/D layout col=lane&15, row=(lane>>4)*4+reg  (m89-verified)
  int lm = lane & 15, lq = lane >> 4;
  float bv[4];
#pragma unroll
  for (int nt = 0; nt < 4; ++nt) bv[nt] = bias[bn + wn + nt * 16 + lm];
#pragma unroll
  for (int mt = 0; mt < 4; ++mt)
#pragma unroll
    for (int r4 = 0; r4 < 4; ++r4) {
      int rowg = bm + wm + mt * 16 + lq * 4 + r4;
      unsigned short* cp = C + (size_t)rowg * Nc + bn + wn + lm;
#pragma unroll
      for (int nt = 0; nt < 4; ++nt)
        cp[nt * 16] = f2bf(acc[mt][nt][r4] + bv[nt]);
    }
}

// ---------- per-channel sum / sumsq over rows (bf16 input) ----------
__global__ void colstats_bf(const unsigned short* __restrict__ Z, int Rr, int C,
                            float* __restrict__ sum, float* __restrict__ sumsq) {
  int c = threadIdx.x;
  int rows = Rr / gridDim.x;
  int r0 = blockIdx.x * rows;
  float s = 0.f, q = 0.f;
  for (int r = r0; r < r0 + rows; ++r) {
    float v = bf2f(Z[(size_t)r * C + c]);
    s += v; q += v * v;
  }
  atomicAdd(&sum[c], s);
  atomicAdd(&sumsq[c], q);
}

__global__ void finalize_bn(const float* __restrict__ sum, const float* __restrict__ sumsq,
                            const float* __restrict__ scale, const float* __restrict__ bias,
                            float* __restrict__ a, float* __restrict__ c,
                            int C, float invR) {
  int j = threadIdx.x;
  if (j >= C) return;
  float mu = sum[j] * invR;
  float var = sumsq[j] * invR - mu * mu;
  float aa = scale[j] * (1.0f / sqrtf(var + 1e-5f));
  a[j] = aa;
  c[j] = bias[j] - mu * aa;
}

// ---------- BN+ReLU + transpose to [B, 128, N] fp32 out ----------
__global__ void out_bn_transpose(const unsigned short* __restrict__ Z1,
                                 const float* __restrict__ a, const float* __restrict__ c,
                                 float* __restrict__ out) {
  __shared__ float tile[32][33];
  int b = blockIdx.z;
  const unsigned short* src = Z1 + (size_t)b * NN * CH2;
  float* dst = out + (size_t)b * CH2 * NN;
  int c0 = blockIdx.x * 32, n0 = blockIdx.y * 32;
  for (int i = threadIdx.y; i < 32; i += 8) {
    int n = n0 + i, ch = c0 + threadIdx.x;
    float v = bf2f(src[(size_t)n * CH2 + ch]);
    v = fmaxf(fmaf(v, a[ch], c[ch]), 0.f);
    tile[i][threadIdx.x] = v;
  }
  __syncthreads();
  for (int i = threadIdx.y; i < 32; i += 8) {
    int ch = c0 + i, n = n0 + threadIdx.x;
    dst[(size_t)ch * NN + n] = tile[threadIdx.x][i];
  }
}

extern "C" void kernel_launch(void* const* d_in, const int* in_sizes, int n_in,
                              void* d_out, int out_size, void* d_ws, size_t ws_size,
                              hipStream_t stream) {
  const float* xyz1    = (const float*)d_in[0];
  const float* xyz2    = (const float*)d_in[1];
  const float* points1 = (const float*)d_in[2];
  const float* points2 = (const float*)d_in[3];
  const float* w0  = (const float*)d_in[4];
  const float* cb0 = (const float*)d_in[5];
  const float* s0  = (const float*)d_in[6];
  const float* bb0 = (const float*)d_in[7];
  const float* w1  = (const float*)d_in[8];
  const float* cb1 = (const float*)d_in[9];
  const float* s1  = (const float*)d_in[10];
  const float* bb1 = (const float*)d_in[11];

  float* ws = (float*)d_ws;
  // layout (float units; all 16B-aligned)
  float*          p2t  = ws;                               // 2,097,152
  float*          p1t  = ws + 2097152;                     // 4,194,304
  int*            idx3 = (int*)(ws + 6291456);             //   196,608
  float*          w3   = ws + 6488064;                     //   196,608
  unsigned short* H0   = (unsigned short*)(ws + 6684672);  // R*192 bf16
  unsigned short* Z0   = (unsigned short*)(ws + 12976128); // R*256 bf16
  unsigned short* Z1   = (unsigned short*)(ws + 21364736); // R*128 bf16
  unsigned short* w0T  = (unsigned short*)(ws + 25559040); // 256*192 bf16
  unsigned short* w1T  = (unsigned short*)(ws + 25583616); // 128*256 bf16
  float*          stats= ws + 25600000;                    //     1,536

  float* sum0 = stats;        float* sq0 = stats + 256;
  float* a0c  = stats + 512;  float* c0c = stats + 768;
  float* sum1 = stats + 1024; float* sq1 = stats + 1152;
  float* a1c  = stats + 1280; float* c1c = stats + 1408;

  hipMemsetAsync(stats, 0, 1536 * sizeof(float), stream);

  // transposes: points2 [B,128,S]->p2t [B,S,128]; points1 [B,64,N]->p1t [B,N,64]
  transpose_k<<<dim3(SS / 32, DD2 / 32, BB), dim3(32, 8), 0, stream>>>(points2, p2t, DD2, SS);
  transpose_k<<<dim3(NN / 32, DD1 / 32, BB), dim3(32, 8), 0, stream>>>(points1, p1t, DD1, NN);
  // weights -> bf16, transposed to [N x K]
  transpose_cvt<<<dim3(CH1 / 32, CIN / 32), dim3(32, 8), 0, stream>>>(w0, w0T, CIN, CH1);
  transpose_cvt<<<dim3(CH2 / 32, CH1 / 32), dim3(32, 8), 0, stream>>>(w1, w1T, CH1, CH2);

  knn3<<<RTOT / 64, 256, 0, stream>>>(xyz1, xyz2, idx3, w3);

  gather_h0<<<RTOT / 2, dim3(192, 2), 0, stream>>>(p1t, p2t, idx3, w3, H0);

  // layer 0: Z0 = H0 @ W0 + b0   (bf16 MFMA)
  gemm_mfma<0, CIN><<<dim3(CH1 / 128, RTOT / 128), 256, 0, stream>>>(
      H0, w0T, cb0, nullptr, nullptr, Z0, CH1);
  colstats_bf<<<512, CH1, 0, stream>>>(Z0, RTOT, CH1, sum0, sq0);
  finalize_bn<<<1, CH1, 0, stream>>>(sum0, sq0, s0, bb0, a0c, c0c, CH1, 1.0f / RTOT);

  // layer 1: Z1 = relu(BN(Z0)) @ W1 + b1  (BN+ReLU fused into A staging)
  gemm_mfma<1, CH1><<<dim3(CH2 / 128, RTOT / 128), 256, 0, stream>>>(
      Z0, w1T, cb1, a0c, c0c, Z1, CH2);
  colstats_bf<<<512, CH2, 0, stream>>>(Z1, RTOT, CH2, sum1, sq1);
  finalize_bn<<<1, CH2, 0, stream>>>(sum1, sq1, s1, bb1, a1c, c1c, CH2, 1.0f / RTOT);

  out_bn_transpose<<<dim3(CH2 / 32, NN / 32, BB), dim3(32, 8), 0, stream>>>(Z1, a1c, c1c,
                                                                            (float*)d_out);
}

// Round 4
// 353.567 us; speedup vs baseline: 1.7677x; 1.0264x over previous
//
#include <hip/hip_runtime.h>

#define BB 8
#define NN 8192
#define SS 2048
#define DD1 64
#define DD2 128
#define CIN 192
#define CH1 256
#define CH2 128
#define RTOT (BB*NN)   // 65536
#define KCHUNK 512
#define NCHK 4

typedef __attribute__((ext_vector_type(8))) short short8;
typedef __attribute__((ext_vector_type(4))) float floatx4;

__device__ __forceinline__ unsigned short f2bf(float f) {
  unsigned u = __float_as_uint(f);
  u += 0x7fff + ((u >> 16) & 1);   // round-to-nearest-even
  return (unsigned short)(u >> 16);
}
__device__ __forceinline__ float bf2f(unsigned short h) {
  return __uint_as_float(((unsigned)h) << 16);
}

// ---------- batched 2D transpose fp32: in [b][rows][cols] -> out [b][cols][rows] ----------
__global__ void transpose_k(const float* __restrict__ in, float* __restrict__ out,
                            int rows, int cols) {
  __shared__ float tile[32][33];
  int b = blockIdx.z;
  const float* src = in + (size_t)b * rows * cols;
  float* dst = out + (size_t)b * rows * cols;
  int c0 = blockIdx.x * 32, r0 = blockIdx.y * 32;
  for (int i = threadIdx.y; i < 32; i += 8)
    tile[i][threadIdx.x] = src[(size_t)(r0 + i) * cols + (c0 + threadIdx.x)];
  __syncthreads();
  for (int i = threadIdx.y; i < 32; i += 8)
    dst[(size_t)(c0 + i) * rows + (r0 + threadIdx.x)] = tile[threadIdx.x][i];
}

// ---------- transpose + fp32->bf16 (for weights; out is [cols][rows] bf16) ----------
__global__ void transpose_cvt(const float* __restrict__ in, unsigned short* __restrict__ out,
                              int rows, int cols) {
  __shared__ float tile[32][33];
  int c0 = blockIdx.x * 32, r0 = blockIdx.y * 32;
  for (int i = threadIdx.y; i < 32; i += 8)
    tile[i][threadIdx.x] = in[(size_t)(r0 + i) * cols + (c0 + threadIdx.x)];
  __syncthreads();
  for (int i = threadIdx.y; i < 32; i += 8)
    out[(size_t)(c0 + i) * rows + (r0 + threadIdx.x)] = f2bf(tile[threadIdx.x][i]);
}

// ---------- 3-NN: fp32 per-chunk top-4 prefilter + fp64 rescore of 16 candidates ----------
// block = 256 threads = 64 rows x 4 chunks of 512. fp32 chunk scan keeps top-4
// (1 slot of margin over the needed top-3 guards fp32 rounding); fp64 rescore
// with (d, idx) lexicographic selection reproduces top_k's exact ranking and
// tie-break (lowest index on equal d).
__global__ __launch_bounds__(256) void knn3(const float* __restrict__ xyz1,
                                            const float* __restrict__ xyz2,
                                            int* __restrict__ idx3,
                                            float* __restrict__ w3) {
  __shared__ __align__(16) float sx[SS];
  __shared__ __align__(16) float sy[SS];
  __shared__ __align__(16) float sz[SS];
  __shared__ int ci[NCHK][64][4];
  int tid = threadIdx.x;
  int r0 = blockIdx.x * 64;
  int b = r0 >> 13;                 // N = 8192
  const float* x2 = xyz2 + (size_t)b * 3 * SS;
  for (int i = tid; i < SS; i += 256) {
    sx[i] = x2[i];
    sy[i] = x2[SS + i];
    sz[i] = x2[2 * SS + i];
  }
  __syncthreads();
  int row = tid & 63, chk = tid >> 6;   // chunk is wave-uniform -> LDS broadcasts
  int n = (r0 & (NN - 1)) + row;
  const float* x1 = xyz1 + (size_t)b * 3 * NN;
  float px = x1[n], py = x1[NN + n], pz = x1[2 * NN + n];
  float c0 = 1e30f, c1 = 1e30f, c2 = 1e30f, c3 = 1e30f;
  int i0 = 0, i1 = 0, i2 = 0, i3 = 0;
  int sbeg = chk * KCHUNK;
  for (int s4 = sbeg; s4 < sbeg + KCHUNK; s4 += 4) {
    floatx4 vx = *(const floatx4*)&sx[s4];
    floatx4 vy = *(const floatx4*)&sy[s4];
    floatx4 vz = *(const floatx4*)&sz[s4];
#pragma unroll
    for (int j = 0; j < 4; ++j) {
      float dx = vx[j] - px, dy = vy[j] - py, dz = vz[j] - pz;
      float d = dx * dx + dy * dy + dz * dz;
      if (d < c3) {
        int s = s4 + j;
        if (d < c2) {
          c3 = c2; i3 = i2;
          if (d < c1) {
            c2 = c1; i2 = i1;
            if (d < c0) { c1 = c0; i1 = i0; c0 = d; i0 = s; }
            else        { c1 = d;  i1 = s; }
          } else { c2 = d; i2 = s; }
        } else { c3 = d; i3 = s; }
      }
    }
  }
  ci[chk][row][0] = i0; ci[chk][row][1] = i1;
  ci[chk][row][2] = i2; ci[chk][row][3] = i3;
  __syncthreads();
  if (tid < 64) {
    double e0 = 1e300, e1 = 1e300, e2 = 1e300;
    int j0 = 0x7fffffff, j1 = 0x7fffffff, j2 = 0x7fffffff;
#pragma unroll
    for (int c = 0; c < NCHK; ++c)
#pragma unroll
      for (int t = 0; t < 4; ++t) {
        int si = ci[c][tid][t];
        double dx = (double)sx[si] - (double)px;
        double dy = (double)sy[si] - (double)py;
        double dz = (double)sz[si] - (double)pz;
        double d = dx * dx + dy * dy + dz * dz;
        if (d < e2 || (d == e2 && si < j2)) {
          if (d < e1 || (d == e1 && si < j1)) {
            e2 = e1; j2 = j1;
            if (d < e0 || (d == e0 && si < j0)) { e1 = e0; j1 = j0; e0 = d; j0 = si; }
            else                                { e1 = d;  j1 = si; }
          } else { e2 = d; j2 = si; }
        }
      }
    double rr0 = 1.0 / (e0 + 1e-8), rr1 = 1.0 / (e1 + 1e-8), rr2 = 1.0 / (e2 + 1e-8);
    double sw = rr0 + rr1 + rr2;
    int r = r0 + tid;
    idx3[r * 3 + 0] = j0; idx3[r * 3 + 1] = j1; idx3[r * 3 + 2] = j2;
    w3[r * 3 + 0] = (float)(rr0 / sw);
    w3[r * 3 + 1] = (float)(rr1 / sw);
    w3[r * 3 + 2] = (float)(rr2 / sw);
  }
}

// ---------- build H0 bf16 [R x 192] = concat(p1t, interp) ----------
__global__ void gather_h0(const float* __restrict__ p1t, const float* __restrict__ p2t,
                          const int* __restrict__ idx3, const float* __restrict__ w3,
                          unsigned short* __restrict__ H0) {
  int r = blockIdx.x * blockDim.y + threadIdx.y;
  int c = threadIdx.x;   // 0..191
  int b = r >> 13;
  float v;
  if (c < DD1) {
    v = p1t[(size_t)r * DD1 + c];
  } else {
    int cc = c - DD1;
    int i0 = idx3[r * 3], i1 = idx3[r * 3 + 1], i2 = idx3[r * 3 + 2];
    float w0 = w3[r * 3], w1 = w3[r * 3 + 1], w2 = w3[r * 3 + 2];
    const float* base = p2t + (size_t)b * SS * DD2;
    v = w0 * base[(size_t)i0 * DD2 + cc]
      + w1 * base[(size_t)i1 * DD2 + cc]
      + w2 * base[(size_t)i2 * DD2 + cc];
  }
  H0[(size_t)r * CIN + c] = f2bf(v);
}

// ---------- bf16 MFMA GEMM: C[M x Nc] = op(A) @ BT^T + bias, bf16 in/out ----------
template<int BNFUSE, int K>
__global__ __launch_bounds__(256) void gemm_mfma(
    const unsigned short* __restrict__ A,
    const unsigned short* __restrict__ BT,
    const float* __restrict__ bias,
    const float* __restrict__ a0, const float* __restrict__ c0,
    unsigned short* __restrict__ C, int Nc)
{
  __shared__ __align__(16) unsigned short As[128 * 32];
  __shared__ __align__(16) unsigned short Bs[128 * 32];
  __shared__ float sa[BNFUSE ? 256 : 1];
  __shared__ float sc[BNFUSE ? 256 : 1];
  int tid = threadIdx.x;
  int lane = tid & 63, w = tid >> 6;
  int bn = blockIdx.x << 7, bm = blockIdx.y << 7;
  int wm = (w & 1) << 6, wn = (w >> 1) << 6;
  if (BNFUSE) {
    for (int i = tid; i < K; i += 256) { sa[i] = a0[i]; sc[i] = c0[i]; }
    __syncthreads();
  }
  floatx4 acc[4][4] = {};   // [mt][nt]
  for (int k0 = 0; k0 < K; k0 += 32) {
    if (!BNFUSE) {
#pragma unroll
      for (int t = 0; t < 2; ++t) {
        int s = (w * 2 + t) * 64 + lane;
        int r = s >> 2;
        int kc = (s & 3) ^ ((r >> 2) & 3);
        const unsigned short* gp = A + (size_t)(bm + r) * K + (k0 + kc * 8);
        __builtin_amdgcn_global_load_lds(
            (const __attribute__((address_space(1))) void*)gp,
            (__attribute__((address_space(3))) void*)(As + (w * 2 + t) * 512),
            16, 0, 0);
      }
    } else {
#pragma unroll
      for (int t = 0; t < 2; ++t) {
        int s = t * 256 + tid;
        int r = s >> 2;
        int kc = (s & 3) ^ ((r >> 2) & 3);
        int kg = k0 + kc * 8;
        short8 raw = *(const short8*)(A + (size_t)(bm + r) * K + kg);
        short8 ov;
#pragma unroll
        for (int j = 0; j < 8; ++j) {
          float v = bf2f((unsigned short)raw[j]);
          v = fmaxf(fmaf(v, sa[kg + j], sc[kg + j]), 0.f);
          ov[j] = (short)f2bf(v);
        }
        *(short8*)(As + s * 8) = ov;
      }
    }
#pragma unroll
    for (int t = 0; t < 2; ++t) {
      int s = (w * 2 + t) * 64 + lane;
      int r = s >> 2;
      int kc = (s & 3) ^ ((r >> 2) & 3);
      const unsigned short* gp = BT + (size_t)(bn + r) * K + (k0 + kc * 8);
      __builtin_amdgcn_global_load_lds(
          (const __attribute__((address_space(1))) void*)gp,
          (__attribute__((address_space(3))) void*)(Bs + (w * 2 + t) * 512),
          16, 0, 0);
    }
    __syncthreads();
    {
      short8 af[4], bfr[4];
      int kcl = lane >> 4;
      int lm = lane & 15;
#pragma unroll
      for (int mt = 0; mt < 4; ++mt) {
        int r = wm + mt * 16 + lm;
        int kp = kcl ^ ((r >> 2) & 3);
        af[mt] = *(const short8*)(As + r * 32 + kp * 8);
      }
#pragma unroll
      for (int nt = 0; nt < 4; ++nt) {
        int r = wn + nt * 16 + lm;
        int kp = kcl ^ ((r >> 2) & 3);
        bfr[nt] = *(const short8*)(Bs + r * 32 + kp * 8);
      }
#pragma unroll
      for (int mt = 0; mt < 4; ++mt)
#pragma unroll
        for (int nt = 0; nt < 4; ++nt)
          acc[mt][nt] = __builtin_amdgcn_mfma_f32_16x16x32_bf16(af[mt], bfr[nt], acc[mt][nt], 0, 0, 0);
    }
    __syncthreads();
  }
  // epilogue: C/D layout col=lane&15, row=(lane>>4)*4+reg  (m89-verified)
  int lm = lane & 15, lq = lane >> 4;
  float bv[4];
#pragma unroll
  for (int nt = 0; nt < 4; ++nt) bv[nt] = bias[bn + wn + nt * 16 + lm];
#pragma unroll
  for (int mt = 0; mt < 4; ++mt)
#pragma unroll
    for (int r4 = 0; r4 < 4; ++r4) {
      int rowg = bm + wm + mt * 16 + lq * 4 + r4;
      unsigned short* cp = C + (size_t)rowg * Nc + bn + wn + lm;
#pragma unroll
      for (int nt = 0; nt < 4; ++nt)
        cp[nt * 16] = f2bf(acc[mt][nt][r4] + bv[nt]);
    }
}

// ---------- per-channel sum / sumsq over rows (bf16 input) ----------
__global__ void colstats_bf(const unsigned short* __restrict__ Z, int Rr, int C,
                            float* __restrict__ sum, float* __restrict__ sumsq) {
  int c = threadIdx.x;
  int rows = Rr / gridDim.x;
  int r0 = blockIdx.x * rows;
  float s = 0.f, q = 0.f;
  for (int r = r0; r < r0 + rows; ++r) {
    float v = bf2f(Z[(size_t)r * C + c]);
    s += v; q += v * v;
  }
  atomicAdd(&sum[c], s);
  atomicAdd(&sumsq[c], q);
}

__global__ void finalize_bn(const float* __restrict__ sum, const float* __restrict__ sumsq,
                            const float* __restrict__ scale, const float* __restrict__ bias,
                            float* __restrict__ a, float* __restrict__ c,
                            int C, float invR) {
  int j = threadIdx.x;
  if (j >= C) return;
  float mu = sum[j] * invR;
  float var = sumsq[j] * invR - mu * mu;
  float aa = scale[j] * (1.0f / sqrtf(var + 1e-5f));
  a[j] = aa;
  c[j] = bias[j] - mu * aa;
}

// ---------- BN+ReLU + transpose to [B, 128, N] fp32 out ----------
__global__ void out_bn_transpose(const unsigned short* __restrict__ Z1,
                                 const float* __restrict__ a, const float* __restrict__ c,
                                 float* __restrict__ out) {
  __shared__ float tile[32][33];
  int b = blockIdx.z;
  const unsigned short* src = Z1 + (size_t)b * NN * CH2;
  float* dst = out + (size_t)b * CH2 * NN;
  int c0 = blockIdx.x * 32, n0 = blockIdx.y * 32;
  for (int i = threadIdx.y; i < 32; i += 8) {
    int n = n0 + i, ch = c0 + threadIdx.x;
    float v = bf2f(src[(size_t)n * CH2 + ch]);
    v = fmaxf(fmaf(v, a[ch], c[ch]), 0.f);
    tile[i][threadIdx.x] = v;
  }
  __syncthreads();
  for (int i = threadIdx.y; i < 32; i += 8) {
    int ch = c0 + i, n = n0 + threadIdx.x;
    dst[(size_t)ch * NN + n] = tile[threadIdx.x][i];
  }
}

extern "C" void kernel_launch(void* const* d_in, const int* in_sizes, int n_in,
                              void* d_out, int out_size, void* d_ws, size_t ws_size,
                              hipStream_t stream) {
  const float* xyz1    = (const float*)d_in[0];
  const float* xyz2    = (const float*)d_in[1];
  const float* points1 = (const float*)d_in[2];
  const float* points2 = (const float*)d_in[3];
  const float* w0  = (const float*)d_in[4];
  const float* cb0 = (const float*)d_in[5];
  const float* s0  = (const float*)d_in[6];
  const float* bb0 = (const float*)d_in[7];
  const float* w1  = (const float*)d_in[8];
  const float* cb1 = (const float*)d_in[9];
  const float* s1  = (const float*)d_in[10];
  const float* bb1 = (const float*)d_in[11];

  float* ws = (float*)d_ws;
  // layout (float units; all 16B-aligned)
  float*          p2t  = ws;                               // 2,097,152
  float*          p1t  = ws + 2097152;                     // 4,194,304
  int*            idx3 = (int*)(ws + 6291456);             //   196,608
  float*          w3   = ws + 6488064;                     //   196,608
  unsigned short* H0   = (unsigned short*)(ws + 6684672);  // R*192 bf16
  unsigned short* Z0   = (unsigned short*)(ws + 12976128); // R*256 bf16
  unsigned short* Z1   = (unsigned short*)(ws + 21364736); // R*128 bf16
  unsigned short* w0T  = (unsigned short*)(ws + 25559040); // 256*192 bf16
  unsigned short* w1T  = (unsigned short*)(ws + 25583616); // 128*256 bf16
  float*          stats= ws + 25600000;                    //     1,536

  float* sum0 = stats;        float* sq0 = stats + 256;
  float* a0c  = stats + 512;  float* c0c = stats + 768;
  float* sum1 = stats + 1024; float* sq1 = stats + 1152;
  float* a1c  = stats + 1280; float* c1c = stats + 1408;

  hipMemsetAsync(stats, 0, 1536 * sizeof(float), stream);

  // transposes: points2 [B,128,S]->p2t [B,S,128]; points1 [B,64,N]->p1t [B,N,64]
  transpose_k<<<dim3(SS / 32, DD2 / 32, BB), dim3(32, 8), 0, stream>>>(points2, p2t, DD2, SS);
  transpose_k<<<dim3(NN / 32, DD1 / 32, BB), dim3(32, 8), 0, stream>>>(points1, p1t, DD1, NN);
  // weights -> bf16, transposed to [N x K]
  transpose_cvt<<<dim3(CH1 / 32, CIN / 32), dim3(32, 8), 0, stream>>>(w0, w0T, CIN, CH1);
  transpose_cvt<<<dim3(CH2 / 32, CH1 / 32), dim3(32, 8), 0, stream>>>(w1, w1T, CH1, CH2);

  knn3<<<RTOT / 64, 256, 0, stream>>>(xyz1, xyz2, idx3, w3);

  gather_h0<<<RTOT / 2, dim3(192, 2), 0, stream>>>(p1t, p2t, idx3, w3, H0);

  // layer 0: Z0 = H0 @ W0 + b0   (bf16 MFMA)
  gemm_mfma<0, CIN><<<dim3(CH1 / 128, RTOT / 128), 256, 0, stream>>>(
      H0, w0T, cb0, nullptr, nullptr, Z0, CH1);
  colstats_bf<<<512, CH1, 0, stream>>>(Z0, RTOT, CH1, sum0, sq0);
  finalize_bn<<<1, CH1, 0, stream>>>(sum0, sq0, s0, bb0, a0c, c0c, CH1, 1.0f / RTOT);

  // layer 1: Z1 = relu(BN(Z0)) @ W1 + b1  (BN+ReLU fused into A staging)
  gemm_mfma<1, CH1><<<dim3(CH2 / 128, RTOT / 128), 256, 0, stream>>>(
      Z0, w1T, cb1, a0c, c0c, Z1, CH2);
  colstats_bf<<<512, CH2, 0, stream>>>(Z1, RTOT, CH2, sum1, sq1);
  finalize_bn<<<1, CH2, 0, stream>>>(sum1, sq1, s1, bb1, a1c, c1c, CH2, 1.0f / RTOT);

  out_bn_transpose<<<dim3(CH2 / 32, NN / 32, BB), dim3(32, 8), 0, stream>>>(Z1, a1c, c1c,
                                                                            (float*)d_out);
}

// Round 5
// 320.806 us; speedup vs baseline: 1.9482x; 1.1021x over previous
//
#include <hip/hip_runtime.h>

#define BB 8
#define NN 8192
#define SS 2048
#define DD1 64
#define DD2 128
#define CIN 192
#define CH1 256
#define CH2 128
#define RTOT (BB*NN)   // 65536
#define KCHUNK 512
#define NCHK 4

typedef __attribute__((ext_vector_type(8))) short short8;
typedef __attribute__((ext_vector_type(4))) float floatx4;

__device__ __forceinline__ unsigned short f2bf(float f) {
  unsigned u = __float_as_uint(f);
  u += 0x7fff + ((u >> 16) & 1);   // round-to-nearest-even
  return (unsigned short)(u >> 16);
}
__device__ __forceinline__ float bf2f(unsigned short h) {
  return __uint_as_float(((unsigned)h) << 16);
}

// ---------- batched 2D transpose fp32: in [b][rows][cols] -> out [b][cols][rows] ----------
__global__ void transpose_k(const float* __restrict__ in, float* __restrict__ out,
                            int rows, int cols) {
  __shared__ float tile[32][33];
  int b = blockIdx.z;
  const float* src = in + (size_t)b * rows * cols;
  float* dst = out + (size_t)b * rows * cols;
  int c0 = blockIdx.x * 32, r0 = blockIdx.y * 32;
  for (int i = threadIdx.y; i < 32; i += 8)
    tile[i][threadIdx.x] = src[(size_t)(r0 + i) * cols + (c0 + threadIdx.x)];
  __syncthreads();
  for (int i = threadIdx.y; i < 32; i += 8)
    dst[(size_t)(c0 + i) * rows + (r0 + threadIdx.x)] = tile[threadIdx.x][i];
}

// ---------- transpose + fp32->bf16 (for weights; out is [cols][rows] bf16) ----------
__global__ void transpose_cvt(const float* __restrict__ in, unsigned short* __restrict__ out,
                              int rows, int cols) {
  __shared__ float tile[32][33];
  int c0 = blockIdx.x * 32, r0 = blockIdx.y * 32;
  for (int i = threadIdx.y; i < 32; i += 8)
    tile[i][threadIdx.x] = in[(size_t)(r0 + i) * cols + (c0 + threadIdx.x)];
  __syncthreads();
  for (int i = threadIdx.y; i < 32; i += 8)
    out[(size_t)(c0 + i) * rows + (r0 + threadIdx.x)] = f2bf(tile[threadIdx.x][i]);
}

// ---------- 3-NN: branchless key-packed fp32 prefilter + fp64 rescore ----------
// key = (bits(d) & ~0x7FF) | s  : float-order-preserving (d>=0), 11-bit idx
// (S=2048), ties -> lower idx, matching top_k. Per-chunk top-4 kept via a
// 7-op integer min/max sorted-insert network (no branches, no cndmask).
// fp64 rescore of the 16 survivors reproduces exact reference ranking.
__global__ __launch_bounds__(256) void knn3(const float* __restrict__ xyz1,
                                            const float* __restrict__ xyz2,
                                            int* __restrict__ idx3,
                                            float* __restrict__ w3) {
  __shared__ __align__(16) float sx[SS];
  __shared__ __align__(16) float sy[SS];
  __shared__ __align__(16) float sz[SS];
  __shared__ unsigned ck[NCHK][64][4];
  int tid = threadIdx.x;
  int r0 = blockIdx.x * 64;
  int b = r0 >> 13;                 // N = 8192
  const float* x2 = xyz2 + (size_t)b * 3 * SS;
  for (int i = tid; i < SS; i += 256) {
    sx[i] = x2[i];
    sy[i] = x2[SS + i];
    sz[i] = x2[2 * SS + i];
  }
  __syncthreads();
  int row = tid & 63, chk = tid >> 6;   // chunk is wave-uniform -> LDS broadcasts
  int n = (r0 & (NN - 1)) + row;
  const float* x1 = xyz1 + (size_t)b * 3 * NN;
  float px = x1[n], py = x1[NN + n], pz = x1[2 * NN + n];
  unsigned c0 = 0xFFFFFFFFu, c1 = 0xFFFFFFFFu, c2 = 0xFFFFFFFFu, c3 = 0xFFFFFFFFu;
  int sbeg = chk * KCHUNK;
  for (int s4 = sbeg; s4 < sbeg + KCHUNK; s4 += 4) {
    floatx4 vx = *(const floatx4*)&sx[s4];
    floatx4 vy = *(const floatx4*)&sy[s4];
    floatx4 vz = *(const floatx4*)&sz[s4];
#pragma unroll
    for (int j = 0; j < 4; ++j) {
      float dx = vx[j] - px, dy = vy[j] - py, dz = vz[j] - pz;
      float d = dx * dx;
      d = fmaf(dy, dy, d);
      d = fmaf(dz, dz, d);
      unsigned k = (__float_as_uint(d) & 0xFFFFF800u) | (unsigned)(s4 + j);
      unsigned m2 = c2 > k ? c2 : k;   // v_max_u32
      unsigned m1 = c1 > k ? c1 : k;
      unsigned m0 = c0 > k ? c0 : k;
      c3 = c3 < m2 ? c3 : m2;          // v_min_u32
      c2 = c2 < m1 ? c2 : m1;
      c1 = c1 < m0 ? c1 : m0;
      c0 = c0 < k ? c0 : k;
    }
  }
  ck[chk][row][0] = c0; ck[chk][row][1] = c1;
  ck[chk][row][2] = c2; ck[chk][row][3] = c3;
  __syncthreads();
  if (tid < 64) {
    double e0 = 1e300, e1 = 1e300, e2 = 1e300;
    int j0 = 0x7fffffff, j1 = 0x7fffffff, j2 = 0x7fffffff;
#pragma unroll
    for (int c = 0; c < NCHK; ++c)
#pragma unroll
      for (int t = 0; t < 4; ++t) {
        int si = (int)(ck[c][tid][t] & 0x7FFu);
        double dx = (double)sx[si] - (double)px;
        double dy = (double)sy[si] - (double)py;
        double dz = (double)sz[si] - (double)pz;
        double d = dx * dx + dy * dy + dz * dz;
        if (d < e2 || (d == e2 && si < j2)) {
          if (d < e1 || (d == e1 && si < j1)) {
            e2 = e1; j2 = j1;
            if (d < e0 || (d == e0 && si < j0)) { e1 = e0; j1 = j0; e0 = d; j0 = si; }
            else                                { e1 = d;  j1 = si; }
          } else { e2 = d; j2 = si; }
        }
      }
    double rr0 = 1.0 / (e0 + 1e-8), rr1 = 1.0 / (e1 + 1e-8), rr2 = 1.0 / (e2 + 1e-8);
    double sw = rr0 + rr1 + rr2;
    int r = r0 + tid;
    idx3[r * 3 + 0] = j0; idx3[r * 3 + 1] = j1; idx3[r * 3 + 2] = j2;
    w3[r * 3 + 0] = (float)(rr0 / sw);
    w3[r * 3 + 1] = (float)(rr1 / sw);
    w3[r * 3 + 2] = (float)(rr2 / sw);
  }
}

// ---------- build H0 bf16 [R x 192] = concat(p1t, interp) ----------
__global__ void gather_h0(const float* __restrict__ p1t, const float* __restrict__ p2t,
                          const int* __restrict__ idx3, const float* __restrict__ w3,
                          unsigned short* __restrict__ H0) {
  int r = blockIdx.x * blockDim.y + threadIdx.y;
  int c = threadIdx.x;   // 0..191
  int b = r >> 13;
  float v;
  if (c < DD1) {
    v = p1t[(size_t)r * DD1 + c];
  } else {
    int cc = c - DD1;
    int i0 = idx3[r * 3], i1 = idx3[r * 3 + 1], i2 = idx3[r * 3 + 2];
    float w0 = w3[r * 3], w1 = w3[r * 3 + 1], w2 = w3[r * 3 + 2];
    const float* base = p2t + (size_t)b * SS * DD2;
    v = w0 * base[(size_t)i0 * DD2 + cc]
      + w1 * base[(size_t)i1 * DD2 + cc]
      + w2 * base[(size_t)i2 * DD2 + cc];
  }
  H0[(size_t)r * CIN + c] = f2bf(v);
}

// ---------- bf16 MFMA GEMM: C[M x Nc] = op(A) @ BT^T + bias, bf16 in/out ----------
template<int BNFUSE, int K>
__global__ __launch_bounds__(256) void gemm_mfma(
    const unsigned short* __restrict__ A,
    const unsigned short* __restrict__ BT,
    const float* __restrict__ bias,
    const float* __restrict__ a0, const float* __restrict__ c0,
    unsigned short* __restrict__ C, int Nc)
{
  __shared__ __align__(16) unsigned short As[128 * 32];
  __shared__ __align__(16) unsigned short Bs[128 * 32];
  __shared__ float sa[BNFUSE ? 256 : 1];
  __shared__ float sc[BNFUSE ? 256 : 1];
  int tid = threadIdx.x;
  int lane = tid & 63, w = tid >> 6;
  int bn = blockIdx.x << 7, bm = blockIdx.y << 7;
  int wm = (w & 1) << 6, wn = (w >> 1) << 6;
  if (BNFUSE) {
    for (int i = tid; i < K; i += 256) { sa[i] = a0[i]; sc[i] = c0[i]; }
    __syncthreads();
  }
  floatx4 acc[4][4] = {};   // [mt][nt]
  for (int k0 = 0; k0 < K; k0 += 32) {
    if (!BNFUSE) {
#pragma unroll
      for (int t = 0; t < 2; ++t) {
        int s = (w * 2 + t) * 64 + lane;
        int r = s >> 2;
        int kc = (s & 3) ^ ((r >> 2) & 3);
        const unsigned short* gp = A + (size_t)(bm + r) * K + (k0 + kc * 8);
        __builtin_amdgcn_global_load_lds(
            (const __attribute__((address_space(1))) void*)gp,
            (__attribute__((address_space(3))) void*)(As + (w * 2 + t) * 512),
            16, 0, 0);
      }
    } else {
#pragma unroll
      for (int t = 0; t < 2; ++t) {
        int s = t * 256 + tid;
        int r = s >> 2;
        int kc = (s & 3) ^ ((r >> 2) & 3);
        int kg = k0 + kc * 8;
        short8 raw = *(const short8*)(A + (size_t)(bm + r) * K + kg);
        short8 ov;
#pragma unroll
        for (int j = 0; j < 8; ++j) {
          float v = bf2f((unsigned short)raw[j]);
          v = fmaxf(fmaf(v, sa[kg + j], sc[kg + j]), 0.f);
          ov[j] = (short)f2bf(v);
        }
        *(short8*)(As + s * 8) = ov;
      }
    }
#pragma unroll
    for (int t = 0; t < 2; ++t) {
      int s = (w * 2 + t) * 64 + lane;
      int r = s >> 2;
      int kc = (s & 3) ^ ((r >> 2) & 3);
      const unsigned short* gp = BT + (size_t)(bn + r) * K + (k0 + kc * 8);
      __builtin_amdgcn_global_load_lds(
          (const __attribute__((address_space(1))) void*)gp,
          (__attribute__((address_space(3))) void*)(Bs + (w * 2 + t) * 512),
          16, 0, 0);
    }
    __syncthreads();
    {
      short8 af[4], bfr[4];
      int kcl = lane >> 4;
      int lm = lane & 15;
#pragma unroll
      for (int mt = 0; mt < 4; ++mt) {
        int r = wm + mt * 16 + lm;
        int kp = kcl ^ ((r >> 2) & 3);
        af[mt] = *(const short8*)(As + r * 32 + kp * 8);
      }
#pragma unroll
      for (int nt = 0; nt < 4; ++nt) {
        int r = wn + nt * 16 + lm;
        int kp = kcl ^ ((r >> 2) & 3);
        bfr[nt] = *(const short8*)(Bs + r * 32 + kp * 8);
      }
#pragma unroll
      for (int mt = 0; mt < 4; ++mt)
#pragma unroll
        for (int nt = 0; nt < 4; ++nt)
          acc[mt][nt] = __builtin_amdgcn_mfma_f32_16x16x32_bf16(af[mt], bfr[nt], acc[mt][nt], 0, 0, 0);
    }
    __syncthreads();
  }
  // epilogue: C/D layout col=lane&15, row=(lane>>4)*4+reg  (m89-verified)
  int lm = lane & 15, lq = lane >> 4;
  float bv[4];
#pragma unroll
  for (int nt = 0; nt < 4; ++nt) bv[nt] = bias[bn + wn + nt * 16 + lm];
#pragma unroll
  for (int mt = 0; mt < 4; ++mt)
#pragma unroll
    for (int r4 = 0; r4 < 4; ++r4) {
      int rowg = bm + wm + mt * 16 + lq * 4 + r4;
      unsigned short* cp = C + (size_t)rowg * Nc + bn + wn + lm;
#pragma unroll
      for (int nt = 0; nt < 4; ++nt)
        cp[nt * 16] = f2bf(acc[mt][nt][r4] + bv[nt]);
    }
}

// ---------- per-channel sum / sumsq over rows (bf16 input) ----------
__global__ void colstats_bf(const unsigned short* __restrict__ Z, int Rr, int C,
                            float* __restrict__ sum, float* __restrict__ sumsq) {
  int c = threadIdx.x;
  int rows = Rr / gridDim.x;
  int r0 = blockIdx.x * rows;
  float s = 0.f, q = 0.f;
  for (int r = r0; r < r0 + rows; ++r) {
    float v = bf2f(Z[(size_t)r * C + c]);
    s += v; q += v * v;
  }
  atomicAdd(&sum[c], s);
  atomicAdd(&sumsq[c], q);
}

__global__ void finalize_bn(const float* __restrict__ sum, const float* __restrict__ sumsq,
                            const float* __restrict__ scale, const float* __restrict__ bias,
                            float* __restrict__ a, float* __restrict__ c,
                            int C, float invR) {
  int j = threadIdx.x;
  if (j >= C) return;
  float mu = sum[j] * invR;
  float var = sumsq[j] * invR - mu * mu;
  float aa = scale[j] * (1.0f / sqrtf(var + 1e-5f));
  a[j] = aa;
  c[j] = bias[j] - mu * aa;
}

// ---------- BN+ReLU + transpose to [B, 128, N] fp32 out ----------
__global__ void out_bn_transpose(const unsigned short* __restrict__ Z1,
                                 const float* __restrict__ a, const float* __restrict__ c,
                                 float* __restrict__ out) {
  __shared__ float tile[32][33];
  int b = blockIdx.z;
  const unsigned short* src = Z1 + (size_t)b * NN * CH2;
  float* dst = out + (size_t)b * CH2 * NN;
  int c0 = blockIdx.x * 32, n0 = blockIdx.y * 32;
  for (int i = threadIdx.y; i < 32; i += 8) {
    int n = n0 + i, ch = c0 + threadIdx.x;
    float v = bf2f(src[(size_t)n * CH2 + ch]);
    v = fmaxf(fmaf(v, a[ch], c[ch]), 0.f);
    tile[i][threadIdx.x] = v;
  }
  __syncthreads();
  for (int i = threadIdx.y; i < 32; i += 8) {
    int ch = c0 + i, n = n0 + threadIdx.x;
    dst[(size_t)ch * NN + n] = tile[threadIdx.x][i];
  }
}

extern "C" void kernel_launch(void* const* d_in, const int* in_sizes, int n_in,
                              void* d_out, int out_size, void* d_ws, size_t ws_size,
                              hipStream_t stream) {
  const float* xyz1    = (const float*)d_in[0];
  const float* xyz2    = (const float*)d_in[1];
  const float* points1 = (const float*)d_in[2];
  const float* points2 = (const float*)d_in[3];
  const float* w0  = (const float*)d_in[4];
  const float* cb0 = (const float*)d_in[5];
  const float* s0  = (const float*)d_in[6];
  const float* bb0 = (const float*)d_in[7];
  const float* w1  = (const float*)d_in[8];
  const float* cb1 = (const float*)d_in[9];
  const float* s1  = (const float*)d_in[10];
  const float* bb1 = (const float*)d_in[11];

  float* ws = (float*)d_ws;
  // layout (float units; all 16B-aligned)
  float*          p2t  = ws;                               // 2,097,152
  float*          p1t  = ws + 2097152;                     // 4,194,304
  int*            idx3 = (int*)(ws + 6291456);             //   196,608
  float*          w3   = ws + 6488064;                     //   196,608
  unsigned short* H0   = (unsigned short*)(ws + 6684672);  // R*192 bf16
  unsigned short* Z0   = (unsigned short*)(ws + 12976128); // R*256 bf16
  unsigned short* Z1   = (unsigned short*)(ws + 21364736); // R*128 bf16
  unsigned short* w0T  = (unsigned short*)(ws + 25559040); // 256*192 bf16
  unsigned short* w1T  = (unsigned short*)(ws + 25583616); // 128*256 bf16
  float*          stats= ws + 25600000;                    //     1,536

  float* sum0 = stats;        float* sq0 = stats + 256;
  float* a0c  = stats + 512;  float* c0c = stats + 768;
  float* sum1 = stats + 1024; float* sq1 = stats + 1152;
  float* a1c  = stats + 1280; float* c1c = stats + 1408;

  hipMemsetAsync(stats, 0, 1536 * sizeof(float), stream);

  // transposes: points2 [B,128,S]->p2t [B,S,128]; points1 [B,64,N]->p1t [B,N,64]
  transpose_k<<<dim3(SS / 32, DD2 / 32, BB), dim3(32, 8), 0, stream>>>(points2, p2t, DD2, SS);
  transpose_k<<<dim3(NN / 32, DD1 / 32, BB), dim3(32, 8), 0, stream>>>(points1, p1t, DD1, NN);
  // weights -> bf16, transposed to [N x K]
  transpose_cvt<<<dim3(CH1 / 32, CIN / 32), dim3(32, 8), 0, stream>>>(w0, w0T, CIN, CH1);
  transpose_cvt<<<dim3(CH2 / 32, CH1 / 32), dim3(32, 8), 0, stream>>>(w1, w1T, CH1, CH2);

  knn3<<<RTOT / 64, 256, 0, stream>>>(xyz1, xyz2, idx3, w3);

  gather_h0<<<RTOT / 2, dim3(192, 2), 0, stream>>>(p1t, p2t, idx3, w3, H0);

  // layer 0: Z0 = H0 @ W0 + b0   (bf16 MFMA)
  gemm_mfma<0, CIN><<<dim3(CH1 / 128, RTOT / 128), 256, 0, stream>>>(
      H0, w0T, cb0, nullptr, nullptr, Z0, CH1);
  colstats_bf<<<512, CH1, 0, stream>>>(Z0, RTOT, CH1, sum0, sq0);
  finalize_bn<<<1, CH1, 0, stream>>>(sum0, sq0, s0, bb0, a0c, c0c, CH1, 1.0f / RTOT);

  // layer 1: Z1 = relu(BN(Z0)) @ W1 + b1  (BN+ReLU fused into A staging)
  gemm_mfma<1, CH1><<<dim3(CH2 / 128, RTOT / 128), 256, 0, stream>>>(
      Z0, w1T, cb1, a0c, c0c, Z1, CH2);
  colstats_bf<<<512, CH2, 0, stream>>>(Z1, RTOT, CH2, sum1, sq1);
  finalize_bn<<<1, CH2, 0, stream>>>(sum1, sq1, s1, bb1, a1c, c1c, CH2, 1.0f / RTOT);

  out_bn_transpose<<<dim3(CH2 / 32, NN / 32, BB), dim3(32, 8), 0, stream>>>(Z1, a1c, c1c,
                                                                            (float*)d_out);
}

// Round 6
// 230.417 us; speedup vs baseline: 2.7124x; 1.3923x over previous
//
#include <hip/hip_runtime.h>

#define BB 8
#define NN 8192
#define SS 2048
#define DD1 64
#define DD2 128
#define CIN 192
#define CH1 256
#define CH2 128
#define RTOT (BB*NN)   // 65536
#define KCHUNK 512
#define NCHK 4

typedef __attribute__((ext_vector_type(8))) short short8;
typedef __attribute__((ext_vector_type(4))) float floatx4;

__device__ __forceinline__ unsigned short f2bf(float f) {
  unsigned u = __float_as_uint(f);
  u += 0x7fff + ((u >> 16) & 1);   // round-to-nearest-even
  return (unsigned short)(u >> 16);
}
__device__ __forceinline__ float bf2f(unsigned short h) {
  return __uint_as_float(((unsigned)h) << 16);
}

// ---------- fused prep: p2t transpose (2048 blks) + w0T (48) + w1T (32) + stats zero (1) ----------
__global__ __launch_bounds__(256) void prep(const float* __restrict__ points2, float* __restrict__ p2t,
                                            const float* __restrict__ w0, unsigned short* __restrict__ w0T,
                                            const float* __restrict__ w1, unsigned short* __restrict__ w1T,
                                            float* __restrict__ stats) {
  __shared__ float tile[32][33];
  int blk = blockIdx.x, tid = threadIdx.x;
  int tx = tid & 31, ty = tid >> 5;
  if (blk < 2048) {          // points2 [B][128][S] -> p2t [B][S][128]
    int z = blk >> 8, rem = blk & 255;
    int gy = rem >> 6, gx = rem & 63;
    const float* src = points2 + (size_t)z * DD2 * SS;
    float* dst = p2t + (size_t)z * DD2 * SS;
    int c0 = gx * 32, r0 = gy * 32;
    for (int i = ty; i < 32; i += 8)
      tile[i][tx] = src[(size_t)(r0 + i) * SS + (c0 + tx)];
    __syncthreads();
    for (int i = ty; i < 32; i += 8)
      dst[(size_t)(c0 + i) * DD2 + (r0 + tx)] = tile[tx][i];
  } else if (blk < 2096) {   // w0 [192][256] -> w0T [256][192] bf16
    int r = blk - 2048;
    int gy = r >> 3, gx = r & 7;
    int c0 = gx * 32, r0 = gy * 32;
    for (int i = ty; i < 32; i += 8)
      tile[i][tx] = w0[(size_t)(r0 + i) * CH1 + (c0 + tx)];
    __syncthreads();
    for (int i = ty; i < 32; i += 8)
      w0T[(size_t)(c0 + i) * CIN + (r0 + tx)] = f2bf(tile[tx][i]);
  } else if (blk < 2128) {   // w1 [256][128] -> w1T [128][256] bf16
    int r = blk - 2096;
    int gy = r >> 2, gx = r & 3;
    int c0 = gx * 32, r0 = gy * 32;
    for (int i = ty; i < 32; i += 8)
      tile[i][tx] = w1[(size_t)(r0 + i) * CH2 + (c0 + tx)];
    __syncthreads();
    for (int i = ty; i < 32; i += 8)
      w1T[(size_t)(c0 + i) * CH1 + (r0 + tx)] = f2bf(tile[tx][i]);
  } else {
    for (int i = tid; i < 768; i += 256) stats[i] = 0.f;
  }
}

// ---------- 3-NN: branchless key-packed fp32 prefilter + fp64 rescore ----------
__global__ __launch_bounds__(256) void knn3(const float* __restrict__ xyz1,
                                            const float* __restrict__ xyz2,
                                            int* __restrict__ idx3,
                                            float* __restrict__ w3) {
  __shared__ __align__(16) float sx[SS];
  __shared__ __align__(16) float sy[SS];
  __shared__ __align__(16) float sz[SS];
  __shared__ unsigned ck[NCHK][64][4];
  int tid = threadIdx.x;
  int r0 = blockIdx.x * 64;
  int b = r0 >> 13;                 // N = 8192
  const float* x2 = xyz2 + (size_t)b * 3 * SS;
  for (int i = tid; i < SS; i += 256) {
    sx[i] = x2[i];
    sy[i] = x2[SS + i];
    sz[i] = x2[2 * SS + i];
  }
  __syncthreads();
  int row = tid & 63, chk = tid >> 6;   // chunk wave-uniform -> LDS broadcasts
  int n = (r0 & (NN - 1)) + row;
  const float* x1 = xyz1 + (size_t)b * 3 * NN;
  float px = x1[n], py = x1[NN + n], pz = x1[2 * NN + n];
  unsigned c0 = 0xFFFFFFFFu, c1 = 0xFFFFFFFFu, c2 = 0xFFFFFFFFu, c3 = 0xFFFFFFFFu;
  int sbeg = chk * KCHUNK;
  for (int s4 = sbeg; s4 < sbeg + KCHUNK; s4 += 4) {
    floatx4 vx = *(const floatx4*)&sx[s4];
    floatx4 vy = *(const floatx4*)&sy[s4];
    floatx4 vz = *(const floatx4*)&sz[s4];
#pragma unroll
    for (int j = 0; j < 4; ++j) {
      float dx = vx[j] - px, dy = vy[j] - py, dz = vz[j] - pz;
      float d = dx * dx;
      d = fmaf(dy, dy, d);
      d = fmaf(dz, dz, d);
      unsigned k = (__float_as_uint(d) & 0xFFFFF800u) | (unsigned)(s4 + j);
      unsigned m2 = __builtin_elementwise_max(c2, k);   // v_max_u32
      unsigned m1 = __builtin_elementwise_max(c1, k);
      unsigned m0 = __builtin_elementwise_max(c0, k);
      c3 = __builtin_elementwise_min(c3, m2);           // v_min_u32
      c2 = __builtin_elementwise_min(c2, m1);
      c1 = __builtin_elementwise_min(c1, m0);
      c0 = __builtin_elementwise_min(c0, k);
    }
  }
  ck[chk][row][0] = c0; ck[chk][row][1] = c1;
  ck[chk][row][2] = c2; ck[chk][row][3] = c3;
  __syncthreads();
  if (tid < 64) {
    double e0 = 1e300, e1 = 1e300, e2 = 1e300;
    int j0 = 0x7fffffff, j1 = 0x7fffffff, j2 = 0x7fffffff;
#pragma unroll
    for (int c = 0; c < NCHK; ++c)
#pragma unroll
      for (int t = 0; t < 4; ++t) {
        int si = (int)(ck[c][tid][t] & 0x7FFu);
        double dx = (double)sx[si] - (double)px;
        double dy = (double)sy[si] - (double)py;
        double dz = (double)sz[si] - (double)pz;
        double d = dx * dx + dy * dy + dz * dz;
        if (d < e2 || (d == e2 && si < j2)) {
          if (d < e1 || (d == e1 && si < j1)) {
            e2 = e1; j2 = j1;
            if (d < e0 || (d == e0 && si < j0)) { e1 = e0; j1 = j0; e0 = d; j0 = si; }
            else                                { e1 = d;  j1 = si; }
          } else { e2 = d; j2 = si; }
        }
      }
    double rr0 = 1.0 / (e0 + 1e-8), rr1 = 1.0 / (e1 + 1e-8), rr2 = 1.0 / (e2 + 1e-8);
    double sw = rr0 + rr1 + rr2;
    int r = r0 + tid;
    idx3[r * 3 + 0] = j0; idx3[r * 3 + 1] = j1; idx3[r * 3 + 2] = j2;
    w3[r * 3 + 0] = (float)(rr0 / sw);
    w3[r * 3 + 1] = (float)(rr1 / sw);
    w3[r * 3 + 2] = (float)(rr2 / sw);
  }
}

// ---------- H0 build, fused p1 transpose: block = 64 rows, dim3(192,2) ----------
__global__ __launch_bounds__(384) void gather_h0(const float* __restrict__ points1,
                                                 const float* __restrict__ p2t,
                                                 const int* __restrict__ idx3,
                                                 const float* __restrict__ w3,
                                                 unsigned short* __restrict__ H0) {
  __shared__ float lds1[64][65];
  __shared__ int   ldsI[64][3];
  __shared__ float ldsW[64][3];
  int tid = threadIdx.y * 192 + threadIdx.x;
  int r0 = blockIdx.x * 64;
  int b = r0 >> 13;
  int n0 = r0 & (NN - 1);
  const float* p1 = points1 + (size_t)b * DD1 * NN;
  for (int i = tid; i < 1024; i += 384) {       // 64ch x 16 float4
    int ch = i >> 4, q = i & 15;
    floatx4 v = *(const floatx4*)(p1 + (size_t)ch * NN + n0 + q * 4);
    lds1[ch][q * 4 + 0] = v[0]; lds1[ch][q * 4 + 1] = v[1];
    lds1[ch][q * 4 + 2] = v[2]; lds1[ch][q * 4 + 3] = v[3];
  }
  if (tid < 64) {
    int r = r0 + tid;
    ldsI[tid][0] = idx3[r * 3];     ldsI[tid][1] = idx3[r * 3 + 1]; ldsI[tid][2] = idx3[r * 3 + 2];
    ldsW[tid][0] = w3[r * 3];       ldsW[tid][1] = w3[r * 3 + 1];   ldsW[tid][2] = w3[r * 3 + 2];
  }
  __syncthreads();
  int c = threadIdx.x;   // waves are fully p1-path (c<64) or fully gather-path
  const float* base = p2t + (size_t)b * SS * DD2;
  int rend = threadIdx.y * 32 + 32;
  for (int rr = threadIdx.y * 32; rr < rend; ++rr) {
    float v;
    if (c < DD1) {
      v = lds1[c][rr];
    } else {
      int cc = c - DD1;
      v = ldsW[rr][0] * base[(size_t)ldsI[rr][0] * DD2 + cc]
        + ldsW[rr][1] * base[(size_t)ldsI[rr][1] * DD2 + cc]
        + ldsW[rr][2] * base[(size_t)ldsI[rr][2] * DD2 + cc];
    }
    H0[(size_t)(r0 + rr) * CIN + c] = f2bf(v);
  }
}

// ---------- bf16 MFMA GEMM + fused column stats (BN batch sums) ----------
// BNFUSE=1: prologue computes BN coeffs from layer-0 sums; A -> relu(a*A+c).
// Epilogue accumulates per-column sum/sumsq of the bf16-rounded outputs.
template<int BNFUSE, int K>
__global__ __launch_bounds__(256) void gemm_mfma(
    const unsigned short* __restrict__ A,
    const unsigned short* __restrict__ BT,
    const float* __restrict__ bias,
    const float* __restrict__ psum, const float* __restrict__ psq,
    const float* __restrict__ pscale, const float* __restrict__ pbias,
    float* __restrict__ osum, float* __restrict__ osq,
    unsigned short* __restrict__ C, int Nc)
{
  __shared__ __align__(16) unsigned short As[128 * 32];
  __shared__ __align__(16) unsigned short Bs[128 * 32];
  __shared__ float sa[BNFUSE ? 256 : 1];
  __shared__ float sc[BNFUSE ? 256 : 1];
  int tid = threadIdx.x;
  int lane = tid & 63, w = tid >> 6;
  int bn = blockIdx.x << 7, bm = blockIdx.y << 7;
  int wm = (w & 1) << 6, wn = (w >> 1) << 6;
  if (BNFUSE) {
    const float invR = 1.0f / RTOT;
    for (int i = tid; i < K; i += 256) {
      float mu = psum[i] * invR;
      float var = psq[i] * invR - mu * mu;
      float aa = pscale[i] * (1.0f / sqrtf(var + 1e-5f));
      sa[i] = aa; sc[i] = pbias[i] - mu * aa;
    }
    __syncthreads();
  }
  floatx4 acc[4][4] = {};   // [mt][nt]
  for (int k0 = 0; k0 < K; k0 += 32) {
    if (!BNFUSE) {
#pragma unroll
      for (int t = 0; t < 2; ++t) {
        int s = (w * 2 + t) * 64 + lane;
        int r = s >> 2;
        int kc = (s & 3) ^ ((r >> 2) & 3);
        const unsigned short* gp = A + (size_t)(bm + r) * K + (k0 + kc * 8);
        __builtin_amdgcn_global_load_lds(
            (const __attribute__((address_space(1))) void*)gp,
            (__attribute__((address_space(3))) void*)(As + (w * 2 + t) * 512),
            16, 0, 0);
      }
    } else {
#pragma unroll
      for (int t = 0; t < 2; ++t) {
        int s = t * 256 + tid;
        int r = s >> 2;
        int kc = (s & 3) ^ ((r >> 2) & 3);
        int kg = k0 + kc * 8;
        short8 raw = *(const short8*)(A + (size_t)(bm + r) * K + kg);
        short8 ov;
#pragma unroll
        for (int j = 0; j < 8; ++j) {
          float v = bf2f((unsigned short)raw[j]);
          v = fmaxf(fmaf(v, sa[kg + j], sc[kg + j]), 0.f);
          ov[j] = (short)f2bf(v);
        }
        *(short8*)(As + s * 8) = ov;
      }
    }
#pragma unroll
    for (int t = 0; t < 2; ++t) {
      int s = (w * 2 + t) * 64 + lane;
      int r = s >> 2;
      int kc = (s & 3) ^ ((r >> 2) & 3);
      const unsigned short* gp = BT + (size_t)(bn + r) * K + (k0 + kc * 8);
      __builtin_amdgcn_global_load_lds(
          (const __attribute__((address_space(1))) void*)gp,
          (__attribute__((address_space(3))) void*)(Bs + (w * 2 + t) * 512),
          16, 0, 0);
    }
    __syncthreads();
    {
      short8 af[4], bfr[4];
      int kcl = lane >> 4;
      int lm = lane & 15;
#pragma unroll
      for (int mt = 0; mt < 4; ++mt) {
        int r = wm + mt * 16 + lm;
        int kp = kcl ^ ((r >> 2) & 3);
        af[mt] = *(const short8*)(As + r * 32 + kp * 8);
      }
#pragma unroll
      for (int nt = 0; nt < 4; ++nt) {
        int r = wn + nt * 16 + lm;
        int kp = kcl ^ ((r >> 2) & 3);
        bfr[nt] = *(const short8*)(Bs + r * 32 + kp * 8);
      }
#pragma unroll
      for (int mt = 0; mt < 4; ++mt)
#pragma unroll
        for (int nt = 0; nt < 4; ++nt)
          acc[mt][nt] = __builtin_amdgcn_mfma_f32_16x16x32_bf16(af[mt], bfr[nt], acc[mt][nt], 0, 0, 0);
    }
    __syncthreads();
  }
  // epilogue: store C (C/D layout col=lane&15, row=(lane>>4)*4+reg) + column stats
  int lm = lane & 15, lq = lane >> 4;
  float bv[4];
#pragma unroll
  for (int nt = 0; nt < 4; ++nt) bv[nt] = bias[bn + wn + nt * 16 + lm];
  float ps[4] = {}, pq[4] = {};
#pragma unroll
  for (int mt = 0; mt < 4; ++mt)
#pragma unroll
    for (int r4 = 0; r4 < 4; ++r4) {
      int rowg = bm + wm + mt * 16 + lq * 4 + r4;
      unsigned short* cp = C + (size_t)rowg * Nc + bn + wn + lm;
#pragma unroll
      for (int nt = 0; nt < 4; ++nt) {
        unsigned short us = f2bf(acc[mt][nt][r4] + bv[nt]);
        cp[nt * 16] = us;
        float vr = bf2f(us);           // stats on the bf16-rounded stored value
        ps[nt] += vr; pq[nt] += vr * vr;
      }
    }
  // block-level column reduction: shuffle over row-quads, LDS-atomic, 1 global atomic/col
  float* colsum = (float*)As;          // reuse LDS (all waves past last barrier)
  float* colsq  = colsum + 128;
  if (tid < 128) { colsum[tid] = 0.f; colsq[tid] = 0.f; }
  __syncthreads();
#pragma unroll
  for (int nt = 0; nt < 4; ++nt) {
    float s = ps[nt], q = pq[nt];
    s += __shfl_down(s, 32); s += __shfl_down(s, 16);
    q += __shfl_down(q, 32); q += __shfl_down(q, 16);
    if (lq == 0) {
      atomicAdd(&colsum[wn + nt * 16 + lm], s);
      atomicAdd(&colsq [wn + nt * 16 + lm], q);
    }
  }
  __syncthreads();
  if (tid < 128) {
    atomicAdd(&osum[bn + tid], colsum[tid]);
    atomicAdd(&osq [bn + tid], colsq[tid]);
  }
}

// ---------- BN+ReLU + transpose to [B, 128, N] fp32; BN coeffs computed in-kernel ----------
__global__ void out_bn_transpose(const unsigned short* __restrict__ Z1,
                                 const float* __restrict__ sum1, const float* __restrict__ sq1,
                                 const float* __restrict__ s1, const float* __restrict__ bb1,
                                 float* __restrict__ out) {
  __shared__ float tile[32][33];
  __shared__ float sa[32], sc[32];
  int b = blockIdx.z;
  int c0 = blockIdx.x * 32, n0 = blockIdx.y * 32;
  int tid = threadIdx.y * 32 + threadIdx.x;
  if (tid < 32) {
    int ch = c0 + tid;
    const float invR = 1.0f / RTOT;
    float mu = sum1[ch] * invR;
    float var = sq1[ch] * invR - mu * mu;
    float aa = s1[ch] * (1.0f / sqrtf(var + 1e-5f));
    sa[tid] = aa; sc[tid] = bb1[ch] - mu * aa;
  }
  __syncthreads();
  const unsigned short* src = Z1 + (size_t)b * NN * CH2;
  float* dst = out + (size_t)b * CH2 * NN;
  for (int i = threadIdx.y; i < 32; i += 8) {
    int n = n0 + i;
    float v = bf2f(src[(size_t)n * CH2 + c0 + threadIdx.x]);
    v = fmaxf(fmaf(v, sa[threadIdx.x], sc[threadIdx.x]), 0.f);
    tile[i][threadIdx.x] = v;
  }
  __syncthreads();
  for (int i = threadIdx.y; i < 32; i += 8) {
    int ch = c0 + i, n = n0 + threadIdx.x;
    dst[(size_t)ch * NN + n] = tile[threadIdx.x][i];
  }
}

extern "C" void kernel_launch(void* const* d_in, const int* in_sizes, int n_in,
                              void* d_out, int out_size, void* d_ws, size_t ws_size,
                              hipStream_t stream) {
  const float* xyz1    = (const float*)d_in[0];
  const float* xyz2    = (const float*)d_in[1];
  const float* points1 = (const float*)d_in[2];
  const float* points2 = (const float*)d_in[3];
  const float* w0  = (const float*)d_in[4];
  const float* cb0 = (const float*)d_in[5];
  const float* s0  = (const float*)d_in[6];
  const float* bb0 = (const float*)d_in[7];
  const float* w1  = (const float*)d_in[8];
  const float* cb1 = (const float*)d_in[9];
  const float* s1  = (const float*)d_in[10];
  const float* bb1 = (const float*)d_in[11];

  float* ws = (float*)d_ws;
  // layout (float units; all 16B-aligned)
  float*          p2t  = ws;                               // 2,097,152
  int*            idx3 = (int*)(ws + 2097152);             //   196,608
  float*          w3   = ws + 2293760;                     //   196,608
  unsigned short* H0   = (unsigned short*)(ws + 2490368);  // R*192 bf16
  unsigned short* Z0   = (unsigned short*)(ws + 8781824);  // R*256 bf16
  unsigned short* Z1   = (unsigned short*)(ws + 17170432); // R*128 bf16
  unsigned short* w0T  = (unsigned short*)(ws + 21364736); // 256*192 bf16
  unsigned short* w1T  = (unsigned short*)(ws + 21389312); // 128*256 bf16
  float*          stats= ws + 21405696;                    //     768

  float* sum0 = stats;        float* sq0 = stats + 256;
  float* sum1 = stats + 512;  float* sq1 = stats + 640;

  // 1: transposes + weight cvt + stats zero (all independent)
  prep<<<2129, 256, 0, stream>>>(points2, p2t, w0, w0T, w1, w1T, stats);

  // 2: 3-NN
  knn3<<<RTOT / 64, 256, 0, stream>>>(xyz1, xyz2, idx3, w3);

  // 3: H0 = concat(p1^T, interp)  (p1 transpose fused via LDS tile)
  gather_h0<<<RTOT / 64, dim3(192, 2), 0, stream>>>(points1, p2t, idx3, w3, H0);

  // 4: Z0 = H0 @ W0 + b0, + column sums for BN0
  gemm_mfma<0, CIN><<<dim3(CH1 / 128, RTOT / 128), 256, 0, stream>>>(
      H0, w0T, cb0, nullptr, nullptr, nullptr, nullptr, sum0, sq0, Z0, CH1);

  // 5: Z1 = relu(BN0(Z0)) @ W1 + b1  (BN coeffs computed in prologue), + sums for BN1
  gemm_mfma<1, CH1><<<dim3(CH2 / 128, RTOT / 128), 256, 0, stream>>>(
      Z0, w1T, cb1, sum0, sq0, s0, bb0, sum1, sq1, Z1, CH2);

  // 6: out = transpose(relu(BN1(Z1)))  (BN coeffs computed in prologue)
  out_bn_transpose<<<dim3(CH2 / 32, NN / 32, BB), dim3(32, 8), 0, stream>>>(
      Z1, sum1, sq1, s1, bb1, (float*)d_out);
}

// Round 8
// 227.550 us; speedup vs baseline: 2.7466x; 1.0126x over previous
//
#include <hip/hip_runtime.h>

#define BB 8
#define NN 8192
#define SS 2048
#define DD1 64
#define DD2 128
#define CIN 192
#define CH1 256
#define CH2 128
#define RTOT (BB*NN)   // 65536
#define KCHUNK 512
#define NCHK 4

typedef __attribute__((ext_vector_type(8))) short short8;
typedef __attribute__((ext_vector_type(4))) float floatx4;

__device__ __forceinline__ unsigned short f2bf(float f) {
  unsigned u = __float_as_uint(f);
  u += 0x7fff + ((u >> 16) & 1);   // round-to-nearest-even
  return (unsigned short)(u >> 16);
}
__device__ __forceinline__ float bf2f(unsigned short h) {
  return __uint_as_float(((unsigned)h) << 16);
}

// ---------- fused prep: p2t transpose (2048 blks) + w0T (48) + w1T (32) + stats zero (1) ----------
__global__ __launch_bounds__(256) void prep(const float* __restrict__ points2, float* __restrict__ p2t,
                                            const float* __restrict__ w0, unsigned short* __restrict__ w0T,
                                            const float* __restrict__ w1, unsigned short* __restrict__ w1T,
                                            float* __restrict__ stats) {
  __shared__ float tile[32][33];
  int blk = blockIdx.x, tid = threadIdx.x;
  int tx = tid & 31, ty = tid >> 5;
  if (blk < 2048) {          // points2 [B][128][S] -> p2t [B][S][128]
    int z = blk >> 8, rem = blk & 255;
    int gy = rem >> 6, gx = rem & 63;
    const float* src = points2 + (size_t)z * DD2 * SS;
    float* dst = p2t + (size_t)z * DD2 * SS;
    int c0 = gx * 32, r0 = gy * 32;
    for (int i = ty; i < 32; i += 8)
      tile[i][tx] = src[(size_t)(r0 + i) * SS + (c0 + tx)];
    __syncthreads();
    for (int i = ty; i < 32; i += 8)
      dst[(size_t)(c0 + i) * DD2 + (r0 + tx)] = tile[tx][i];
  } else if (blk < 2096) {   // w0 [192][256] -> w0T [256][192] bf16
    int r = blk - 2048;
    int gy = r >> 3, gx = r & 7;
    int c0 = gx * 32, r0 = gy * 32;
    for (int i = ty; i < 32; i += 8)
      tile[i][tx] = w0[(size_t)(r0 + i) * CH1 + (c0 + tx)];
    __syncthreads();
    for (int i = ty; i < 32; i += 8)
      w0T[(size_t)(c0 + i) * CIN + (r0 + tx)] = f2bf(tile[tx][i]);
  } else if (blk < 2128) {   // w1 [256][128] -> w1T [128][256] bf16
    int r = blk - 2096;
    int gy = r >> 2, gx = r & 3;
    int c0 = gx * 32, r0 = gy * 32;
    for (int i = ty; i < 32; i += 8)
      tile[i][tx] = w1[(size_t)(r0 + i) * CH2 + (c0 + tx)];
    __syncthreads();
    for (int i = ty; i < 32; i += 8)
      w1T[(size_t)(c0 + i) * CH1 + (r0 + tx)] = f2bf(tile[tx][i]);
  } else {
    for (int i = tid; i < 768; i += 256) stats[i] = 0.f;
  }
}

// ---------- fused 3-NN + H0 build ----------
// Phase B: branchless key-packed fp32 prefilter, per-chunk top-4
//          (key = (bits(d) & ~0x7FF) | s ; order-preserving, ties -> lower idx)
// Phase C: fp64 rescore of 16 survivors -> exact reference ranking + weights (LDS)
// Phase E: H0[r, 0:64] = p1^T tile (LDS-staged), H0[r, 64:192] = 3-NN interp
__global__ __launch_bounds__(256) void knn3_gather(const float* __restrict__ xyz1,
                                                   const float* __restrict__ xyz2,
                                                   const float* __restrict__ points1,
                                                   const float* __restrict__ p2t,
                                                   unsigned short* __restrict__ H0) {
  __shared__ __align__(16) union LU {
    float coords[3][SS];     // 24 KB, phases A-C
    float p1t[64][65];       // 16.6 KB, phases D-E (coords dead)
  } u;
  __shared__ unsigned ck[NCHK][64][4];
  __shared__ int   ldsI[64][3];
  __shared__ float ldsW[64][3];
  int tid = threadIdx.x;
  int r0 = blockIdx.x * 64;
  int b = r0 >> 13;                 // N = 8192
  int n0 = r0 & (NN - 1);
  const float* x2 = xyz2 + (size_t)b * 3 * SS;
  for (int i = tid; i < SS; i += 256) {
    u.coords[0][i] = x2[i];
    u.coords[1][i] = x2[SS + i];
    u.coords[2][i] = x2[2 * SS + i];
  }
  __syncthreads();
  int row = tid & 63, chk = tid >> 6;   // chunk wave-uniform -> LDS broadcasts
  int n = n0 + row;
  const float* x1 = xyz1 + (size_t)b * 3 * NN;
  float px = x1[n], py = x1[NN + n], pz = x1[2 * NN + n];
  unsigned c0 = 0xFFFFFFFFu, c1 = 0xFFFFFFFFu, c2 = 0xFFFFFFFFu, c3 = 0xFFFFFFFFu;
  int sbeg = (int)__builtin_amdgcn_readfirstlane((unsigned)(chk * KCHUNK));
  for (int s8 = sbeg; s8 < sbeg + KCHUNK; s8 += 8) {
    float xs[8], ys[8], zs[8];
    *(floatx4*)&xs[0] = *(const floatx4*)&u.coords[0][s8];
    *(floatx4*)&xs[4] = *(const floatx4*)&u.coords[0][s8 + 4];
    *(floatx4*)&ys[0] = *(const floatx4*)&u.coords[1][s8];
    *(floatx4*)&ys[4] = *(const floatx4*)&u.coords[1][s8 + 4];
    *(floatx4*)&zs[0] = *(const floatx4*)&u.coords[2][s8];
    *(floatx4*)&zs[4] = *(const floatx4*)&u.coords[2][s8 + 4];
#pragma unroll
    for (int j = 0; j < 8; ++j) {
      float dx = xs[j] - px, dy = ys[j] - py, dz = zs[j] - pz;
      float d = dx * dx;
      d = fmaf(dy, dy, d);
      d = fmaf(dz, dz, d);
      unsigned k = (__float_as_uint(d) & 0xFFFFF800u) | (unsigned)(s8 + j);
      unsigned m2 = __builtin_elementwise_max(c2, k);   // v_max_u32
      unsigned m1 = __builtin_elementwise_max(c1, k);
      unsigned m0 = __builtin_elementwise_max(c0, k);
      c3 = __builtin_elementwise_min(c3, m2);           // v_min_u32
      c2 = __builtin_elementwise_min(c2, m1);
      c1 = __builtin_elementwise_min(c1, m0);
      c0 = __builtin_elementwise_min(c0, k);
    }
  }
  ck[chk][row][0] = c0; ck[chk][row][1] = c1;
  ck[chk][row][2] = c2; ck[chk][row][3] = c3;
  // prefetch the p1 tile into registers: latency hides under the rescore
  floatx4 pv[4];
  const float* p1 = points1 + (size_t)b * DD1 * NN;
#pragma unroll
  for (int t = 0; t < 4; ++t) {
    int i = tid + t * 256;             // 0..1023 = 64ch x 16 float4
    int ch = i >> 4, q = i & 15;
    pv[t] = *(const floatx4*)(p1 + (size_t)ch * NN + n0 + q * 4);
  }
  __syncthreads();
  if (tid < 64) {
    float qpx = x1[n0 + tid], qpy = x1[NN + n0 + tid], qpz = x1[2 * NN + n0 + tid];
    double e0 = 1e300, e1 = 1e300, e2 = 1e300;
    int j0 = 0x7fffffff, j1 = 0x7fffffff, j2 = 0x7fffffff;
#pragma unroll
    for (int c = 0; c < NCHK; ++c)
#pragma unroll
      for (int t = 0; t < 4; ++t) {
        int si = (int)(ck[c][tid][t] & 0x7FFu);
        double dx = (double)u.coords[0][si] - (double)qpx;
        double dy = (double)u.coords[1][si] - (double)qpy;
        double dz = (double)u.coords[2][si] - (double)qpz;
        double d = dx * dx + dy * dy + dz * dz;
        if (d < e2 || (d == e2 && si < j2)) {
          if (d < e1 || (d == e1 && si < j1)) {
            e2 = e1; j2 = j1;
            if (d < e0 || (d == e0 && si < j0)) { e1 = e0; j1 = j0; e0 = d; j0 = si; }
            else                                { e1 = d;  j1 = si; }
          } else { e2 = d; j2 = si; }
        }
      }
    double rr0 = 1.0 / (e0 + 1e-8), rr1 = 1.0 / (e1 + 1e-8), rr2 = 1.0 / (e2 + 1e-8);
    double sw = rr0 + rr1 + rr2;
    ldsI[tid][0] = j0; ldsI[tid][1] = j1; ldsI[tid][2] = j2;
    ldsW[tid][0] = (float)(rr0 / sw);
    ldsW[tid][1] = (float)(rr1 / sw);
    ldsW[tid][2] = (float)(rr2 / sw);
  }
  __syncthreads();                      // coords dead; p1t region live
#pragma unroll
  for (int t = 0; t < 4; ++t) {
    int i = tid + t * 256;
    int ch = i >> 4, q = i & 15;
    u.p1t[ch][q * 4 + 0] = pv[t][0];    // component stores: [64][65] stays 2-way max
    u.p1t[ch][q * 4 + 1] = pv[t][1];
    u.p1t[ch][q * 4 + 2] = pv[t][2];
    u.p1t[ch][q * 4 + 3] = pv[t][3];
  }
  __syncthreads();
  const float* base = p2t + (size_t)b * SS * DD2;
  unsigned short* Hrow = H0 + (size_t)r0 * CIN;
  for (int i = tid; i < 64 * CIN; i += 256) {   // c-block uniform per wave per iter
    int rr = i / CIN;
    int c = i - rr * CIN;
    float v;
    if (c < DD1) {
      v = u.p1t[c][rr];
    } else {
      int cc = c - DD1;
      v = ldsW[rr][0] * base[(size_t)ldsI[rr][0] * DD2 + cc]
        + ldsW[rr][1] * base[(size_t)ldsI[rr][1] * DD2 + cc]
        + ldsW[rr][2] * base[(size_t)ldsI[rr][2] * DD2 + cc];
    }
    Hrow[i] = f2bf(v);                  // linear index -> coalesced bf16 stores
  }
}

// ---------- bf16 MFMA GEMM + fused column stats (BN batch sums) ----------
template<int BNFUSE, int K>
__global__ __launch_bounds__(256) void gemm_mfma(
    const unsigned short* __restrict__ A,
    const unsigned short* __restrict__ BT,
    const float* __restrict__ bias,
    const float* __restrict__ psum, const float* __restrict__ psq,
    const float* __restrict__ pscale, const float* __restrict__ pbias,
    float* __restrict__ osum, float* __restrict__ osq,
    unsigned short* __restrict__ C, int Nc)
{
  __shared__ __align__(16) unsigned short As[128 * 32];
  __shared__ __align__(16) unsigned short Bs[128 * 32];
  __shared__ float sa[BNFUSE ? 256 : 1];
  __shared__ float sc[BNFUSE ? 256 : 1];
  int tid = threadIdx.x;
  int lane = tid & 63, w = tid >> 6;
  int bn = blockIdx.x << 7, bm = blockIdx.y << 7;
  int wm = (w & 1) << 6, wn = (w >> 1) << 6;
  if (BNFUSE) {
    const float invR = 1.0f / RTOT;
    for (int i = tid; i < K; i += 256) {
      float mu = psum[i] * invR;
      float var = psq[i] * invR - mu * mu;
      float aa = pscale[i] * (1.0f / sqrtf(var + 1e-5f));
      sa[i] = aa; sc[i] = pbias[i] - mu * aa;
    }
    __syncthreads();
  }
  floatx4 acc[4][4] = {};   // [mt][nt]
  for (int k0 = 0; k0 < K; k0 += 32) {
    if (!BNFUSE) {
#pragma unroll
      for (int t = 0; t < 2; ++t) {
        int s = (w * 2 + t) * 64 + lane;
        int r = s >> 2;
        int kc = (s & 3) ^ ((r >> 2) & 3);
        const unsigned short* gp = A + (size_t)(bm + r) * K + (k0 + kc * 8);
        __builtin_amdgcn_global_load_lds(
            (const __attribute__((address_space(1))) void*)gp,
            (__attribute__((address_space(3))) void*)(As + (w * 2 + t) * 512),
            16, 0, 0);
      }
    } else {
#pragma unroll
      for (int t = 0; t < 2; ++t) {
        int s = t * 256 + tid;
        int r = s >> 2;
        int kc = (s & 3) ^ ((r >> 2) & 3);
        int kg = k0 + kc * 8;
        short8 raw = *(const short8*)(A + (size_t)(bm + r) * K + kg);
        short8 ov;
#pragma unroll
        for (int j = 0; j < 8; ++j) {
          float v = bf2f((unsigned short)raw[j]);
          v = fmaxf(fmaf(v, sa[kg + j], sc[kg + j]), 0.f);
          ov[j] = (short)f2bf(v);
        }
        *(short8*)(As + s * 8) = ov;
      }
    }
#pragma unroll
    for (int t = 0; t < 2; ++t) {
      int s = (w * 2 + t) * 64 + lane;
      int r = s >> 2;
      int kc = (s & 3) ^ ((r >> 2) & 3);
      const unsigned short* gp = BT + (size_t)(bn + r) * K + (k0 + kc * 8);
      __builtin_amdgcn_global_load_lds(
          (const __attribute__((address_space(1))) void*)gp,
          (__attribute__((address_space(3))) void*)(Bs + (w * 2 + t) * 512),
          16, 0, 0);
    }
    __syncthreads();
    {
      short8 af[4], bfr[4];
      int kcl = lane >> 4;
      int lm = lane & 15;
#pragma unroll
      for (int mt = 0; mt < 4; ++mt) {
        int r = wm + mt * 16 + lm;
        int kp = kcl ^ ((r >> 2) & 3);
        af[mt] = *(const short8*)(As + r * 32 + kp * 8);
      }
#pragma unroll
      for (int nt = 0; nt < 4; ++nt) {
        int r = wn + nt * 16 + lm;
        int kp = kcl ^ ((r >> 2) & 3);
        bfr[nt] = *(const short8*)(Bs + r * 32 + kp * 8);
      }
#pragma unroll
      for (int mt = 0; mt < 4; ++mt)
#pragma unroll
        for (int nt = 0; nt < 4; ++nt)
          acc[mt][nt] = __builtin_amdgcn_mfma_f32_16x16x32_bf16(af[mt], bfr[nt], acc[mt][nt], 0, 0, 0);
    }
    __syncthreads();
  }
  // epilogue: store C (C/D layout col=lane&15, row=(lane>>4)*4+reg) + column stats
  int lm = lane & 15, lq = lane >> 4;
  float bv[4];
#pragma unroll
  for (int nt = 0; nt < 4; ++nt) bv[nt] = bias[bn + wn + nt * 16 + lm];
  float ps[4] = {}, pq[4] = {};
#pragma unroll
  for (int mt = 0; mt < 4; ++mt)
#pragma unroll
    for (int r4 = 0; r4 < 4; ++r4) {
      int rowg = bm + wm + mt * 16 + lq * 4 + r4;
      unsigned short* cp = C + (size_t)rowg * Nc + bn + wn + lm;
#pragma unroll
      for (int nt = 0; nt < 4; ++nt) {
        unsigned short us = f2bf(acc[mt][nt][r4] + bv[nt]);
        cp[nt * 16] = us;
        float vr = bf2f(us);           // stats on the bf16-rounded stored value
        ps[nt] += vr; pq[nt] += vr * vr;
      }
    }
  float* colsum = (float*)As;          // reuse LDS (all waves past last barrier)
  float* colsq  = colsum + 128;
  if (tid < 128) { colsum[tid] = 0.f; colsq[tid] = 0.f; }
  __syncthreads();
#pragma unroll
  for (int nt = 0; nt < 4; ++nt) {
    float s = ps[nt], q = pq[nt];
    s += __shfl_down(s, 32); s += __shfl_down(s, 16);
    q += __shfl_down(q, 32); q += __shfl_down(q, 16);
    if (lq == 0) {
      atomicAdd(&colsum[wn + nt * 16 + lm], s);
      atomicAdd(&colsq [wn + nt * 16 + lm], q);
    }
  }
  __syncthreads();
  if (tid < 128) {
    atomicAdd(&osum[bn + tid], colsum[tid]);
    atomicAdd(&osq [bn + tid], colsq[tid]);
  }
}

// ---------- BN+ReLU + transpose to [B, 128, N] fp32; BN coeffs computed in-kernel ----------
__global__ void out_bn_transpose(const unsigned short* __restrict__ Z1,
                                 const float* __restrict__ sum1, const float* __restrict__ sq1,
                                 const float* __restrict__ s1, const float* __restrict__ bb1,
                                 float* __restrict__ out) {
  __shared__ float tile[32][33];
  __shared__ float sa[32], sc[32];
  int b = blockIdx.z;
  int c0 = blockIdx.x * 32, n0 = blockIdx.y * 32;
  int tid = threadIdx.y * 32 + threadIdx.x;
  if (tid < 32) {
    int ch = c0 + tid;
    const float invR = 1.0f / RTOT;
    float mu = sum1[ch] * invR;
    float var = sq1[ch] * invR - mu * mu;
    float aa = s1[ch] * (1.0f / sqrtf(var + 1e-5f));
    sa[tid] = aa; sc[tid] = bb1[ch] - mu * aa;
  }
  __syncthreads();
  const unsigned short* src = Z1 + (size_t)b * NN * CH2;
  float* dst = out + (size_t)b * CH2 * NN;
  for (int i = threadIdx.y; i < 32; i += 8) {
    int n = n0 + i;
    float v = bf2f(src[(size_t)n * CH2 + c0 + threadIdx.x]);
    v = fmaxf(fmaf(v, sa[threadIdx.x], sc[threadIdx.x]), 0.f);
    tile[i][threadIdx.x] = v;
  }
  __syncthreads();
  for (int i = threadIdx.y; i < 32; i += 8) {
    int ch = c0 + i, n = n0 + threadIdx.x;
    dst[(size_t)ch * NN + n] = tile[threadIdx.x][i];
  }
}

extern "C" void kernel_launch(void* const* d_in, const int* in_sizes, int n_in,
                              void* d_out, int out_size, void* d_ws, size_t ws_size,
                              hipStream_t stream) {
  const float* xyz1    = (const float*)d_in[0];
  const float* xyz2    = (const float*)d_in[1];
  const float* points1 = (const float*)d_in[2];
  const float* points2 = (const float*)d_in[3];
  const float* w0  = (const float*)d_in[4];
  const float* cb0 = (const float*)d_in[5];
  const float* s0  = (const float*)d_in[6];
  const float* bb0 = (const float*)d_in[7];
  const float* w1  = (const float*)d_in[8];
  const float* cb1 = (const float*)d_in[9];
  const float* s1  = (const float*)d_in[10];
  const float* bb1 = (const float*)d_in[11];

  float* ws = (float*)d_ws;
  // layout (float units; all 16B-aligned)
  float*          p2t  = ws;                               // 2,097,152
  unsigned short* H0   = (unsigned short*)(ws + 2097152);  // R*192 bf16
  unsigned short* Z0   = (unsigned short*)(ws + 8388608);  // R*256 bf16
  unsigned short* Z1   = (unsigned short*)(ws + 16777216); // R*128 bf16
  unsigned short* w0T  = (unsigned short*)(ws + 20971520); //    24,576
  unsigned short* w1T  = (unsigned short*)(ws + 20996096); //    16,384
  float*          stats= ws + 21012480;                    //       768

  float* sum0 = stats;        float* sq0 = stats + 256;
  float* sum1 = stats + 512;  float* sq1 = stats + 640;

  // 1: transposes + weight cvt + stats zero (all independent)
  prep<<<2129, 256, 0, stream>>>(points2, p2t, w0, w0T, w1, w1T, stats);

  // 2: 3-NN + interp + H0 build (fused)
  knn3_gather<<<RTOT / 64, 256, 0, stream>>>(xyz1, xyz2, points1, p2t, H0);

  // 3: Z0 = H0 @ W0 + b0, + column sums for BN0
  gemm_mfma<0, CIN><<<dim3(CH1 / 128, RTOT / 128), 256, 0, stream>>>(
      H0, w0T, cb0, nullptr, nullptr, nullptr, nullptr, sum0, sq0, Z0, CH1);

  // 4: Z1 = relu(BN0(Z0)) @ W1 + b1  (BN coeffs in prologue), + sums for BN1
  gemm_mfma<1, CH1><<<dim3(CH2 / 128, RTOT / 128), 256, 0, stream>>>(
      Z0, w1T, cb1, sum0, sq0, s0, bb0, sum1, sq1, Z1, CH2);

  // 5: out = transpose(relu(BN1(Z1)))  (BN coeffs in prologue)
  out_bn_transpose<<<dim3(CH2 / 32, NN / 32, BB), dim3(32, 8), 0, stream>>>(
      Z1, sum1, sq1, s1, bb1, (float*)d_out);
}

// Round 9
// 223.418 us; speedup vs baseline: 2.7974x; 1.0185x over previous
//
#include <hip/hip_runtime.h>

#define BB 8
#define NN 8192
#define SS 2048
#define DD1 64
#define DD2 128
#define CIN 192
#define CH1 256
#define CH2 128
#define RTOT (BB*NN)   // 65536
#define KCHUNK 512
#define NCHK 4

typedef __attribute__((ext_vector_type(8))) short short8;
typedef __attribute__((ext_vector_type(4))) short shortx4;
typedef __attribute__((ext_vector_type(4))) float floatx4;
typedef __attribute__((ext_vector_type(2))) float floatx2;

__device__ __forceinline__ unsigned short f2bf(float f) {
  unsigned u = __float_as_uint(f);
  u += 0x7fff + ((u >> 16) & 1);   // round-to-nearest-even
  return (unsigned short)(u >> 16);
}
__device__ __forceinline__ float bf2f(unsigned short h) {
  return __uint_as_float(((unsigned)h) << 16);
}

// ---------- fused prep: p2t transpose (2048 blks) + w0T (48) + w1T (32) + stats zero (1) ----------
__global__ __launch_bounds__(256) void prep(const float* __restrict__ points2, float* __restrict__ p2t,
                                            const float* __restrict__ w0, unsigned short* __restrict__ w0T,
                                            const float* __restrict__ w1, unsigned short* __restrict__ w1T,
                                            float* __restrict__ stats) {
  __shared__ float tile[32][33];
  int blk = blockIdx.x, tid = threadIdx.x;
  int tx = tid & 31, ty = tid >> 5;
  if (blk < 2048) {          // points2 [B][128][S] -> p2t [B][S][128]
    int z = blk >> 8, rem = blk & 255;
    int gy = rem >> 6, gx = rem & 63;
    const float* src = points2 + (size_t)z * DD2 * SS;
    float* dst = p2t + (size_t)z * DD2 * SS;
    int c0 = gx * 32, r0 = gy * 32;
    for (int i = ty; i < 32; i += 8)
      tile[i][tx] = src[(size_t)(r0 + i) * SS + (c0 + tx)];
    __syncthreads();
    for (int i = ty; i < 32; i += 8)
      dst[(size_t)(c0 + i) * DD2 + (r0 + tx)] = tile[tx][i];
  } else if (blk < 2096) {   // w0 [192][256] -> w0T [256][192] bf16
    int r = blk - 2048;
    int gy = r >> 3, gx = r & 7;
    int c0 = gx * 32, r0 = gy * 32;
    for (int i = ty; i < 32; i += 8)
      tile[i][tx] = w0[(size_t)(r0 + i) * CH1 + (c0 + tx)];
    __syncthreads();
    for (int i = ty; i < 32; i += 8)
      w0T[(size_t)(c0 + i) * CIN + (r0 + tx)] = f2bf(tile[tx][i]);
  } else if (blk < 2128) {   // w1 [256][128] -> w1T [128][256] bf16
    int r = blk - 2096;
    int gy = r >> 2, gx = r & 3;
    int c0 = gx * 32, r0 = gy * 32;
    for (int i = ty; i < 32; i += 8)
      tile[i][tx] = w1[(size_t)(r0 + i) * CH2 + (c0 + tx)];
    __syncthreads();
    for (int i = ty; i < 32; i += 8)
      w1T[(size_t)(c0 + i) * CH1 + (r0 + tx)] = f2bf(tile[tx][i]);
  } else {
    for (int i = tid; i < 768; i += 256) stats[i] = 0.f;
  }
}

// ---------- fused 3-NN + H0 build ----------
// Phase B: key-packed fp32 prefilter on float2 pairs (targets v_pk_* codegen),
//          per-chunk top-4 via 7-op u32 min/max network.
// Phase C: fp64 rescore of 16 survivors -> exact reference ranking + weights.
// Phase E: H0[r,0:64] = p1^T (LDS tile), H0[r,64:192] = interp, float4 gathers.
__global__ __launch_bounds__(256) void knn3_gather(const float* __restrict__ xyz1,
                                                   const float* __restrict__ xyz2,
                                                   const float* __restrict__ points1,
                                                   const float* __restrict__ p2t,
                                                   unsigned short* __restrict__ H0) {
  __shared__ __align__(16) union LU {
    float coords[3][SS];     // 24 KB, phases A-C
    float p1t[64][65];       // 16.6 KB, phases D-E (coords dead)
  } u;
  __shared__ unsigned ck[NCHK][64][4];
  __shared__ int   ldsI[64][3];
  __shared__ float ldsW[64][3];
  int tid = threadIdx.x;
  int r0 = blockIdx.x * 64;
  int b = r0 >> 13;                 // N = 8192
  int n0 = r0 & (NN - 1);
  const float* x2 = xyz2 + (size_t)b * 3 * SS;
  for (int i = tid; i < SS; i += 256) {
    u.coords[0][i] = x2[i];
    u.coords[1][i] = x2[SS + i];
    u.coords[2][i] = x2[2 * SS + i];
  }
  __syncthreads();
  int row = tid & 63, chk = tid >> 6;   // chunk wave-uniform -> LDS broadcasts
  int n = n0 + row;
  const float* x1 = xyz1 + (size_t)b * 3 * NN;
  float px = x1[n], py = x1[NN + n], pz = x1[2 * NN + n];
  floatx2 px2 = {px, px}, py2 = {py, py}, pz2 = {pz, pz};
  unsigned c0 = 0xFFFFFFFFu, c1 = 0xFFFFFFFFu, c2 = 0xFFFFFFFFu, c3 = 0xFFFFFFFFu;
  int sbeg = (int)__builtin_amdgcn_readfirstlane((unsigned)(chk * KCHUNK));
  for (int s8 = sbeg; s8 < sbeg + KCHUNK; s8 += 8) {
#pragma unroll
    for (int p = 0; p < 4; ++p) {
      floatx2 xv = *(const floatx2*)&u.coords[0][s8 + 2 * p];
      floatx2 yv = *(const floatx2*)&u.coords[1][s8 + 2 * p];
      floatx2 zv = *(const floatx2*)&u.coords[2][s8 + 2 * p];
      floatx2 dx = xv - px2, dy = yv - py2, dz = zv - pz2;
      floatx2 d = dx * dx + dy * dy + dz * dz;   // contracts to mul+2fma (pk hoped)
#pragma unroll
      for (int e = 0; e < 2; ++e) {
        float dd = (e == 0) ? d.x : d.y;
        unsigned k = (__float_as_uint(dd) & 0xFFFFF800u) | (unsigned)(s8 + 2 * p + e);
        unsigned m2 = __builtin_elementwise_max(c2, k);   // v_max_u32
        unsigned m1 = __builtin_elementwise_max(c1, k);
        unsigned m0 = __builtin_elementwise_max(c0, k);
        c3 = __builtin_elementwise_min(c3, m2);           // v_min_u32
        c2 = __builtin_elementwise_min(c2, m1);
        c1 = __builtin_elementwise_min(c1, m0);
        c0 = __builtin_elementwise_min(c0, k);
      }
    }
  }
  ck[chk][row][0] = c0; ck[chk][row][1] = c1;
  ck[chk][row][2] = c2; ck[chk][row][3] = c3;
  // prefetch the p1 tile into registers: latency hides under the rescore
  floatx4 pv[4];
  const float* p1 = points1 + (size_t)b * DD1 * NN;
#pragma unroll
  for (int t = 0; t < 4; ++t) {
    int i = tid + t * 256;             // 0..1023 = 64ch x 16 float4
    int ch = i >> 4, q = i & 15;
    pv[t] = *(const floatx4*)(p1 + (size_t)ch * NN + n0 + q * 4);
  }
  __syncthreads();
  if (tid < 64) {
    float qpx = x1[n0 + tid], qpy = x1[NN + n0 + tid], qpz = x1[2 * NN + n0 + tid];
    double e0 = 1e300, e1 = 1e300, e2 = 1e300;
    int j0 = 0x7fffffff, j1 = 0x7fffffff, j2 = 0x7fffffff;
#pragma unroll
    for (int c = 0; c < NCHK; ++c)
#pragma unroll
      for (int t = 0; t < 4; ++t) {
        int si = (int)(ck[c][tid][t] & 0x7FFu);
        double dx = (double)u.coords[0][si] - (double)qpx;
        double dy = (double)u.coords[1][si] - (double)qpy;
        double dz = (double)u.coords[2][si] - (double)qpz;
        double d = dx * dx + dy * dy + dz * dz;
        if (d < e2 || (d == e2 && si < j2)) {
          if (d < e1 || (d == e1 && si < j1)) {
            e2 = e1; j2 = j1;
            if (d < e0 || (d == e0 && si < j0)) { e1 = e0; j1 = j0; e0 = d; j0 = si; }
            else                                { e1 = d;  j1 = si; }
          } else { e2 = d; j2 = si; }
        }
      }
    double rr0 = 1.0 / (e0 + 1e-8), rr1 = 1.0 / (e1 + 1e-8), rr2 = 1.0 / (e2 + 1e-8);
    double sw = rr0 + rr1 + rr2;
    ldsI[tid][0] = j0; ldsI[tid][1] = j1; ldsI[tid][2] = j2;
    ldsW[tid][0] = (float)(rr0 / sw);
    ldsW[tid][1] = (float)(rr1 / sw);
    ldsW[tid][2] = (float)(rr2 / sw);
  }
  __syncthreads();                      // coords dead; p1t region live
#pragma unroll
  for (int t = 0; t < 4; ++t) {
    int i = tid + t * 256;
    int ch = i >> 4, q = i & 15;
    u.p1t[ch][q * 4 + 0] = pv[t][0];    // component stores: [64][65] stays 2-way max
    u.p1t[ch][q * 4 + 1] = pv[t][1];
    u.p1t[ch][q * 4 + 2] = pv[t][2];
    u.p1t[ch][q * 4 + 3] = pv[t][3];
  }
  __syncthreads();
  const float* base = p2t + (size_t)b * SS * DD2;
  unsigned short* Hrow = H0 + (size_t)r0 * CIN;
  for (int i = tid; i < 64 * 48; i += 256) {   // quad-columns: 48 per row
    int rr = i / 48;
    int qc = i - rr * 48;
    floatx4 v;
    if (qc < 16) {
      v[0] = u.p1t[qc * 4 + 0][rr];
      v[1] = u.p1t[qc * 4 + 1][rr];
      v[2] = u.p1t[qc * 4 + 2][rr];
      v[3] = u.p1t[qc * 4 + 3][rr];
    } else {
      int cc = qc * 4 - DD1;
      floatx4 g0 = *(const floatx4*)(base + (size_t)ldsI[rr][0] * DD2 + cc);
      floatx4 g1 = *(const floatx4*)(base + (size_t)ldsI[rr][1] * DD2 + cc);
      floatx4 g2 = *(const floatx4*)(base + (size_t)ldsI[rr][2] * DD2 + cc);
      float w0 = ldsW[rr][0], w1 = ldsW[rr][1], w2 = ldsW[rr][2];
#pragma unroll
      for (int e = 0; e < 4; ++e)
        v[e] = w0 * g0[e] + w1 * g1[e] + w2 * g2[e];
    }
    shortx4 pk;
#pragma unroll
    for (int e = 0; e < 4; ++e) pk[e] = (short)f2bf(v[e]);
    *(shortx4*)(Hrow + (size_t)rr * CIN + qc * 4) = pk;   // 8B coalesced stores
  }
}

// ---------- bf16 MFMA GEMM + fused column stats (BN batch sums) ----------
// BNFUSE=1: prologue computes BN coeffs from layer-0 sums; A -> relu(a*A+c).
// TRANSP=1: C written transposed as [B][CH2][NN] bf16 (short4 n-runs).
template<int BNFUSE, int K, int TRANSP>
__global__ __launch_bounds__(256) void gemm_mfma(
    const unsigned short* __restrict__ A,
    const unsigned short* __restrict__ BT,
    const float* __restrict__ bias,
    const float* __restrict__ psum, const float* __restrict__ psq,
    const float* __restrict__ pscale, const float* __restrict__ pbias,
    float* __restrict__ osum, float* __restrict__ osq,
    unsigned short* __restrict__ C, int Nc)
{
  __shared__ __align__(16) unsigned short As[128 * 32];
  __shared__ __align__(16) unsigned short Bs[128 * 32];
  __shared__ float sa[BNFUSE ? 256 : 1];
  __shared__ float sc[BNFUSE ? 256 : 1];
  int tid = threadIdx.x;
  int lane = tid & 63, w = tid >> 6;
  int bn = blockIdx.x << 7, bm = blockIdx.y << 7;
  int wm = (w & 1) << 6, wn = (w >> 1) << 6;
  if (BNFUSE) {
    const float invR = 1.0f / RTOT;
    for (int i = tid; i < K; i += 256) {
      float mu = psum[i] * invR;
      float var = psq[i] * invR - mu * mu;
      float aa = pscale[i] * (1.0f / sqrtf(var + 1e-5f));
      sa[i] = aa; sc[i] = pbias[i] - mu * aa;
    }
    __syncthreads();
  }
  floatx4 acc[4][4] = {};   // [mt][nt]
  for (int k0 = 0; k0 < K; k0 += 32) {
    if (!BNFUSE) {
#pragma unroll
      for (int t = 0; t < 2; ++t) {
        int s = (w * 2 + t) * 64 + lane;
        int r = s >> 2;
        int kc = (s & 3) ^ ((r >> 2) & 3);
        const unsigned short* gp = A + (size_t)(bm + r) * K + (k0 + kc * 8);
        __builtin_amdgcn_global_load_lds(
            (const __attribute__((address_space(1))) void*)gp,
            (__attribute__((address_space(3))) void*)(As + (w * 2 + t) * 512),
            16, 0, 0);
      }
    } else {
#pragma unroll
      for (int t = 0; t < 2; ++t) {
        int s = t * 256 + tid;
        int r = s >> 2;
        int kc = (s & 3) ^ ((r >> 2) & 3);
        int kg = k0 + kc * 8;
        short8 raw = *(const short8*)(A + (size_t)(bm + r) * K + kg);
        short8 ov;
#pragma unroll
        for (int j = 0; j < 8; ++j) {
          float v = bf2f((unsigned short)raw[j]);
          v = fmaxf(fmaf(v, sa[kg + j], sc[kg + j]), 0.f);
          ov[j] = (short)f2bf(v);
        }
        *(short8*)(As + s * 8) = ov;
      }
    }
#pragma unroll
    for (int t = 0; t < 2; ++t) {
      int s = (w * 2 + t) * 64 + lane;
      int r = s >> 2;
      int kc = (s & 3) ^ ((r >> 2) & 3);
      const unsigned short* gp = BT + (size_t)(bn + r) * K + (k0 + kc * 8);
      __builtin_amdgcn_global_load_lds(
          (const __attribute__((address_space(1))) void*)gp,
          (__attribute__((address_space(3))) void*)(Bs + (w * 2 + t) * 512),
          16, 0, 0);
    }
    __syncthreads();
    {
      short8 af[4], bfr[4];
      int kcl = lane >> 4;
      int lm = lane & 15;
#pragma unroll
      for (int mt = 0; mt < 4; ++mt) {
        int r = wm + mt * 16 + lm;
        int kp = kcl ^ ((r >> 2) & 3);
        af[mt] = *(const short8*)(As + r * 32 + kp * 8);
      }
#pragma unroll
      for (int nt = 0; nt < 4; ++nt) {
        int r = wn + nt * 16 + lm;
        int kp = kcl ^ ((r >> 2) & 3);
        bfr[nt] = *(const short8*)(Bs + r * 32 + kp * 8);
      }
#pragma unroll
      for (int mt = 0; mt < 4; ++mt)
#pragma unroll
        for (int nt = 0; nt < 4; ++nt)
          acc[mt][nt] = __builtin_amdgcn_mfma_f32_16x16x32_bf16(af[mt], bfr[nt], acc[mt][nt], 0, 0, 0);
    }
    __syncthreads();
  }
  // epilogue: store C (C/D layout col=lane&15, row=(lane>>4)*4+reg) + column stats
  int lm = lane & 15, lq = lane >> 4;
  float bv[4];
#pragma unroll
  for (int nt = 0; nt < 4; ++nt) bv[nt] = bias[bn + wn + nt * 16 + lm];
  float ps[4] = {}, pq[4] = {};
  if (!TRANSP) {
#pragma unroll
    for (int mt = 0; mt < 4; ++mt)
#pragma unroll
      for (int r4 = 0; r4 < 4; ++r4) {
        int rowg = bm + wm + mt * 16 + lq * 4 + r4;
        unsigned short* cp = C + (size_t)rowg * Nc + bn + wn + lm;
#pragma unroll
        for (int nt = 0; nt < 4; ++nt) {
          unsigned short us = f2bf(acc[mt][nt][r4] + bv[nt]);
          cp[nt * 16] = us;
          float vr = bf2f(us);           // stats on the bf16-rounded stored value
          ps[nt] += vr; pq[nt] += vr * vr;
        }
      }
  } else {
    int bq = bm >> 13;                   // batch (bm multiple of 128, 8192%128==0)
    int nbase = (bm & (NN - 1)) + wm + lq * 4;
#pragma unroll
    for (int mt = 0; mt < 4; ++mt) {
      int nn = nbase + mt * 16;
#pragma unroll
      for (int nt = 0; nt < 4; ++nt) {
        int ch = wn + nt * 16 + lm;      // bn == 0 for CH2=128
        shortx4 pk;
#pragma unroll
        for (int r4 = 0; r4 < 4; ++r4) {
          unsigned short us = f2bf(acc[mt][nt][r4] + bv[nt]);
          pk[r4] = (short)us;
          float vr = bf2f(us);
          ps[nt] += vr; pq[nt] += vr * vr;
        }
        *(shortx4*)(C + (((size_t)(bq * CH2 + ch)) << 13) + nn) = pk;
      }
    }
  }
  float* colsum = (float*)As;          // reuse LDS (all waves past last barrier)
  float* colsq  = colsum + 128;
  if (tid < 128) { colsum[tid] = 0.f; colsq[tid] = 0.f; }
  __syncthreads();
#pragma unroll
  for (int nt = 0; nt < 4; ++nt) {
    float s = ps[nt], q = pq[nt];
    s += __shfl_down(s, 32); s += __shfl_down(s, 16);
    q += __shfl_down(q, 32); q += __shfl_down(q, 16);
    if (lq == 0) {
      atomicAdd(&colsum[wn + nt * 16 + lm], s);
      atomicAdd(&colsq [wn + nt * 16 + lm], q);
    }
  }
  __syncthreads();
  if (tid < 128) {
    atomicAdd(&osum[bn + tid], colsum[tid]);
    atomicAdd(&osq [bn + tid], colsq[tid]);
  }
}

// ---------- elementwise BN+ReLU + fp32 convert: zT [B][128][N] bf16 -> out fp32 ----------
__global__ __launch_bounds__(256) void out_cvt(const unsigned short* __restrict__ zT,
                                               const float* __restrict__ sum1, const float* __restrict__ sq1,
                                               const float* __restrict__ s1, const float* __restrict__ bb1,
                                               float* __restrict__ out) {
  size_t gid = (size_t)blockIdx.x * 256 + threadIdx.x;
  size_t base = gid * 8;                       // 8 elems/thread, one n-row segment
  int ch = (int)((base >> 13) & (CH2 - 1));
  const float invR = 1.0f / RTOT;
  float mu = sum1[ch] * invR;
  float var = sq1[ch] * invR - mu * mu;
  float a = s1[ch] * (1.0f / sqrtf(var + 1e-5f));
  float c = bb1[ch] - mu * a;
  short8 z = *(const short8*)(zT + base);
  floatx4 o0, o1;
#pragma unroll
  for (int j = 0; j < 4; ++j) o0[j] = fmaxf(fmaf(bf2f((unsigned short)z[j]), a, c), 0.f);
#pragma unroll
  for (int j = 0; j < 4; ++j) o1[j] = fmaxf(fmaf(bf2f((unsigned short)z[j + 4]), a, c), 0.f);
  *(floatx4*)(out + base) = o0;
  *(floatx4*)(out + base + 4) = o1;
}

extern "C" void kernel_launch(void* const* d_in, const int* in_sizes, int n_in,
                              void* d_out, int out_size, void* d_ws, size_t ws_size,
                              hipStream_t stream) {
  const float* xyz1    = (const float*)d_in[0];
  const float* xyz2    = (const float*)d_in[1];
  const float* points1 = (const float*)d_in[2];
  const float* points2 = (const float*)d_in[3];
  const float* w0  = (const float*)d_in[4];
  const float* cb0 = (const float*)d_in[5];
  const float* s0  = (const float*)d_in[6];
  const float* bb0 = (const float*)d_in[7];
  const float* w1  = (const float*)d_in[8];
  const float* cb1 = (const float*)d_in[9];
  const float* s1  = (const float*)d_in[10];
  const float* bb1 = (const float*)d_in[11];

  float* ws = (float*)d_ws;
  // layout (float units; all 16B-aligned)
  float*          p2t  = ws;                               // 2,097,152
  unsigned short* H0   = (unsigned short*)(ws + 2097152);  // R*192 bf16
  unsigned short* Z0   = (unsigned short*)(ws + 8388608);  // R*256 bf16
  unsigned short* zT   = (unsigned short*)(ws + 16777216); // R*128 bf16, [B][128][N]
  unsigned short* w0T  = (unsigned short*)(ws + 20971520); //    24,576
  unsigned short* w1T  = (unsigned short*)(ws + 20996096); //    16,384
  float*          stats= ws + 21012480;                    //       768

  float* sum0 = stats;        float* sq0 = stats + 256;
  float* sum1 = stats + 512;  float* sq1 = stats + 640;

  // 1: transposes + weight cvt + stats zero (all independent)
  prep<<<2129, 256, 0, stream>>>(points2, p2t, w0, w0T, w1, w1T, stats);

  // 2: 3-NN + interp + H0 build (fused)
  knn3_gather<<<RTOT / 64, 256, 0, stream>>>(xyz1, xyz2, points1, p2t, H0);

  // 3: Z0 = H0 @ W0 + b0, + column sums for BN0
  gemm_mfma<0, CIN, 0><<<dim3(CH1 / 128, RTOT / 128), 256, 0, stream>>>(
      H0, w0T, cb0, nullptr, nullptr, nullptr, nullptr, sum0, sq0, Z0, CH1);

  // 4: zT = (relu(BN0(Z0)) @ W1 + b1)^T  (BN coeffs in prologue), + sums for BN1
  gemm_mfma<1, CH1, 1><<<dim3(CH2 / 128, RTOT / 128), 256, 0, stream>>>(
      Z0, w1T, cb1, sum0, sq0, s0, bb0, sum1, sq1, zT, CH2);

  // 5: out = relu(BN1(zT)) as fp32, pure elementwise
  out_cvt<<<RTOT * CH2 / 8 / 256, 256, 0, stream>>>(
      zT, sum1, sq1, s1, bb1, (float*)d_out);
}